// Round 3
// baseline (1049.398 us; speedup 1.0000x reference)
//
#include <hip/hip_runtime.h>

#define S_ 2048
#define F_ 512
#define I_ 1024
#define C_ 256

typedef float f4 __attribute__((ext_vector_type(4)));
typedef __bf16 bf8 __attribute__((ext_vector_type(8)));
typedef __bf16 bf4 __attribute__((ext_vector_type(4)));
typedef int i4v __attribute__((ext_vector_type(4)));
typedef int i8v __attribute__((ext_vector_type(8)));
typedef unsigned char u8;

__device__ __forceinline__ void gload_lds16(const void* g, void* l) {
  __builtin_amdgcn_global_load_lds(
      (const __attribute__((address_space(1))) void*)g,
      (__attribute__((address_space(3))) void*)l, 16, 0, 0);
}

__device__ __forceinline__ float fe_val(int f) {
  const float PI_F = 3.14159265358979323846f;
  float additive = (f & 1) ? 0.0f : 1.0f;
  float fv = ((float)(f + 1) - additive) * 0.5f;
  fv = fv * (8.0f / (float)F_) - logf((float)C_ / (2.0f * PI_F));
  return expf(fv) + additive * PI_F;
}

// MX-fp8 GEMM. C[n][m] = (1/64)*sum_k A[m][k]*B'[k][n].
// KW=3 causal: k = t*KD + j, B row (n + t - 2), zero page if < 0.
// OUT: 0 = f32, 2 = fp8-e4m3. Output n-major (ldc = M).
//
// R9 structure (post-R7/R8 failures: dbuf@64KB lost occupancy, k-rotation
// lost L2 sharing):
//  - A fragments load DIRECTLY from global into registers (weights are
//    L2/L3-resident; the R6 LDS swizzle composed to identity: lane (l15,quad)
//    needs chunks 2q,2q+1 of row m0+wr*64+mt*16+l15 = 32 contiguous bytes).
//    Halves LDS staging, removes Asm entirely.
//  - B double-buffered in the freed LDS (2x NTILE*128 = 32 KB for NTILE=128,
//    same footprint as R6 -> 3 blocks/CU preserved, balanced 768-block grid).
//    stageB(k+1) issues BEFORE compute(k): the barrier's vmcnt(0) drain lands
//    after ~550cy of MFMA cover instead of exposing full L2 latency.
//  - Natural k-order (no rotation) keeps inter-block L2 tile sharing.
//  - Single A reg buffer (reload right after consumption) keeps VGPR <= ~150
//    so 3 waves/SIMD survive; launch_bounds(256,3) pins the allocator.
template <int KW, bool RELU, int OUT, int NTILE, int KD, int LDB>
__global__ __launch_bounds__(256, 3) void gemm_f8(
    const u8* __restrict__ Ab, const u8* __restrict__ Bb, void* __restrict__ Cb,
    const u8* __restrict__ zpage, int M, int PZ, long sAp, long sBp, long sBb,
    long sCz) {
  constexpr int NF = NTILE / 32;  // n-frags per wave
  constexpr int NIT = KD / 128;   // 128-byte k-steps per segment
  constexpr int AK = KW * KD;     // A row stride
  constexpr int BP = NTILE / 32;  // B staging passes (32 rows each)
  constexpr int NSTEP = KW * NIT;
  static_assert(NSTEP % 2 == 0, "even k-step count required");
  __shared__ u8 Bsm[2][NTILE * 128];
  const int tid = threadIdx.x;
  const int z = blockIdx.z;
  const int p = z % PZ;
  const int bb = z / PZ;
  const u8* A = Ab + (long)p * sAp;
  const u8* B = Bb + (long)bb * sBb + (long)p * sBp;
  const int m0 = blockIdx.y * 128;
  const int n0 = blockIdx.x * NTILE;
  const int lane = tid & 63;
  const int wave = tid >> 6;
  const int wr = wave >> 1;
  const int wc = wave & 1;
  const int l15 = lane & 15;
  const int quad = lane >> 4;
  const int cr = tid >> 3;                        // staged row within pass
  const int csw = (((tid & 7) ^ (cr & 7)) << 4);  // fetched chunk
  const int off0 = (((2 * quad) ^ (l15 & 7)) << 4);
  const int off1 = (((2 * quad + 1) ^ (l15 & 7)) << 4);
  f4 acc[4][NF] = {};

  // Per-mt A row base (includes the lane's 32-byte chunk offset quad*32).
  const u8* Arow[4];
#pragma unroll
  for (int mt = 0; mt < 4; ++mt)
    Arow[mt] = A + (long)(m0 + wr * 64 + mt * 16 + l15) * AK + quad * 32;

  // Load A fragments for k-step ks directly from global into registers.
  auto loadA = [&](int ks, i8v* ar) {
    const int t = (KW == 1) ? 0 : (ks / NIT);
    const long o = (long)t * KD + (ks & (NIT - 1)) * 128;
#pragma unroll
    for (int mt = 0; mt < 4; ++mt) {
      const i4v lo = *(const i4v*)(Arow[mt] + o);
      const i4v hi = *(const i4v*)(Arow[mt] + o + 16);
      ar[mt][0] = lo[0]; ar[mt][1] = lo[1]; ar[mt][2] = lo[2]; ar[mt][3] = lo[3];
      ar[mt][4] = hi[0]; ar[mt][5] = hi[1]; ar[mt][6] = hi[2]; ar[mt][7] = hi[3];
    }
  };

  // Stage B k-slice for k-step ks into LDS buffer buf (R6 swizzled layout).
  auto stageB = [&](int ks, int buf) {
    const int t = (KW == 1) ? 0 : (ks / NIT);
    const int kb = (ks & (NIT - 1)) * 128;
#pragma unroll
    for (int g = 0; g < BP; ++g) {
      const int rg = n0 + g * 32 + cr + ((KW == 3) ? (t - 2) : 0);
      const u8* pB = (KW == 3 && rg < 0) ? (zpage + csw)
                                         : (B + (long)rg * LDB + kb + csw);
      gload_lds16(pB, &Bsm[buf][g * 4096 + wave * 1024]);
    }
  };

  // ds_read B fragments from Bsm[buf] + 16/8 MFMAs with A regs.
  auto compute = [&](const i8v* ar, int buf) {
    i8v bfr[NF];
#pragma unroll
    for (int nt = 0; nt < NF; ++nt) {
      const u8* rp = &Bsm[buf][(wc * (NTILE / 2) + nt * 16 + l15) * 128];
      const i4v lo = *(const i4v*)(rp + off0);
      const i4v hi = *(const i4v*)(rp + off1);
      bfr[nt][0] = lo[0]; bfr[nt][1] = lo[1]; bfr[nt][2] = lo[2]; bfr[nt][3] = lo[3];
      bfr[nt][4] = hi[0]; bfr[nt][5] = hi[1]; bfr[nt][6] = hi[2]; bfr[nt][7] = hi[3];
    }
    __builtin_amdgcn_s_setprio(1);
#pragma unroll
    for (int mt = 0; mt < 4; ++mt)
#pragma unroll
      for (int nt = 0; nt < NF; ++nt)
        acc[mt][nt] = __builtin_amdgcn_mfma_scale_f32_16x16x128_f8f6f4(
            ar[mt], bfr[nt], acc[mt][nt], 0, 0, 0, 0x7F7F7F7F, 0, 0x7F7F7F7F);
    __builtin_amdgcn_s_setprio(0);
  };

  i8v aA[4];
  loadA(0, aA);
  stageB(0, 0);
  __syncthreads();  // buf0 ready
#pragma unroll 1
  for (int ks = 0; ks < NSTEP; ks += 2) {
    stageB(ks + 1, 1);     // in flight under compute
    compute(aA, 0);
    loadA(ks + 1, aA);     // reload after consumption (WAR handled by compiler)
    __syncthreads();       // drains stage(ks+1) + A loads; frees buf0
    if (ks + 2 < NSTEP) stageB(ks + 2, 0);
    compute(aA, 1);
    if (ks + 2 < NSTEP) loadA(ks + 2, aA);
    __syncthreads();
  }

#pragma unroll
  for (int mt = 0; mt < 4; ++mt) {
    const int m = m0 + wr * 64 + mt * 16 + quad * 4;
#pragma unroll
    for (int nt = 0; nt < NF; ++nt) {
      const int n = n0 + wc * (NTILE / 2) + nt * 16 + l15;
      f4 v = acc[mt][nt];
#pragma unroll
      for (int q = 0; q < 4; ++q) {
        v[q] *= 0.015625f;  // undo weight x64
        if (RELU) v[q] = fmaxf(v[q], 0.0f);
      }
      if (OUT == 2) {
        int r = __builtin_amdgcn_cvt_pk_fp8_f32(v[0], v[1], 0, false);
        r = __builtin_amdgcn_cvt_pk_fp8_f32(v[2], v[3], r, true);
        *(int*)((u8*)Cb + (long)z * sCz + (long)n * M + m) = r;
      } else {
        *(f4*)((float*)Cb + (long)z * sCz + (long)n * M + m) = v;
      }
    }
  }
}

__device__ __forceinline__ void cvt4(const float* __restrict__ s,
                                     __bf16* __restrict__ d, long T) {
  const long i = T * 4;
  const float4 v = *(const float4*)(s + i);
  bf4 o;
  o[0] = (__bf16)v.x;
  o[1] = (__bf16)v.y;
  o[2] = (__bf16)v.z;
  o[3] = (__bf16)v.w;
  *(bf4*)(d + i) = o;
}

__device__ __forceinline__ void cvt4f8(const float* __restrict__ s,
                                       u8* __restrict__ d, long T) {
  const long i = T * 4;
  const float4 v = *(const float4*)(s + i);
  int r = __builtin_amdgcn_cvt_pk_fp8_f32(v.x * 64.0f, v.y * 64.0f, 0, false);
  r = __builtin_amdgcn_cvt_pk_fp8_f32(v.z * 64.0f, v.w * 64.0f, r, true);
  *(int*)(d + i) = r;
}

__device__ __forceinline__ int pk4f8(float a, float b, float c, float d) {
  int r = __builtin_amdgcn_cvt_pk_fp8_f32(a, b, 0, false);
  return __builtin_amdgcn_cvt_pk_fp8_f32(c, d, r, true);
}

// One dispatch: w0s/w2s -> fp8 x64, out_w -> bf16, w1s reorder -> fp8 x64.
// w1 path vectorized: thread handles 4 j's (3 float4 reads, 3 int stores).
__global__ void k_prep(const float* __restrict__ w0, const float* __restrict__ w2,
                       const float* __restrict__ ow, const float* __restrict__ w1,
                       u8* __restrict__ W0f8, u8* __restrict__ W2f8,
                       __bf16* __restrict__ OWc, u8* __restrict__ W1f8) {
  long T = (long)blockIdx.x * 256 + threadIdx.x;
  if (T < 786432L) {
    cvt4f8(w0, W0f8, T);
    return;
  }
  T -= 786432L;
  if (T < 786432L) {
    cvt4f8(w2, W2f8, T);
    return;
  }
  T -= 786432L;
  if (T < 65536L) {
    cvt4(ow, OWc, T);
    return;
  }
  T -= 65536L;
  // w1s (L,3,I,I,K=3) -> W1f8[(l*3+p)*I+i][t*1024 + j], value x64
  const long j4 = T & 255;   // group of 4 j's
  const long r3 = T >> 8;
  const float* src = w1 + r3 * 3072 + j4 * 12;
  const float4 v0 = *(const float4*)src;       // j0t0 j0t1 j0t2 j1t0
  const float4 v1 = *(const float4*)(src + 4); // j1t1 j1t2 j2t0 j2t1
  const float4 v2 = *(const float4*)(src + 8); // j2t2 j3t0 j3t1 j3t2
  u8* dst = W1f8 + r3 * 3072 + j4 * 4;
  *(int*)(dst) = pk4f8(v0.x * 64.f, v0.w * 64.f, v1.z * 64.f, v2.y * 64.f);
  *(int*)(dst + 1024) = pk4f8(v0.y * 64.f, v1.x * 64.f, v1.w * 64.f, v2.z * 64.f);
  *(int*)(dst + 2048) = pk4f8(v0.z * 64.f, v1.y * 64.f, v2.x * 64.f, v2.w * 64.f);
}

// One wave per (b,s): gather embedding -> a/b state (f32) + layer-0 h (fp8).
__global__ __launch_bounds__(64) void k_embed(const int* __restrict__ inp,
                                              const float* __restrict__ emb,
                                              float* __restrict__ a_st,
                                              float* __restrict__ b_st,
                                              u8* __restrict__ h) {
  const int col = blockIdx.x;
  const int lane = threadIdx.x;
  const int f0 = lane * 8;
  const float* e = emb + (long)inp[col] * (2 * F_);
  const float4 a0 = *(const float4*)(e + f0);
  const float4 a1 = *(const float4*)(e + f0 + 4);
  const float4 b0 = *(const float4*)(e + F_ + f0);
  const float4 b1 = *(const float4*)(e + F_ + f0 + 4);
  *(float4*)(a_st + (long)col * F_ + f0) = a0;
  *(float4*)(a_st + (long)col * F_ + f0 + 4) = a1;
  *(float4*)(b_st + (long)col * F_ + f0) = b0;
  *(float4*)(b_st + (long)col * F_ + f0 + 4) = b1;
  const float bb[8] = {b0.x, b0.y, b0.z, b0.w, b1.x, b1.y, b1.z, b1.w};
  float hv[8];
#pragma unroll
  for (int q = 0; q < 8; ++q) hv[q] = bb[q] + fe_val(f0 + q);
  const int lo = pk4f8(hv[0], hv[1], hv[2], hv[3]);
  const int hi = pk4f8(hv[4], hv[5], hv[6], hv[7]);
  *(int2*)(h + (long)col * F_ + f0) = {lo, hi};
}

// One wave per (b,s) column: shfl-scan cumsum, stats, EMA; fuse next h (fp8)
// or final streams (bf16).
__global__ __launch_bounds__(64) void k_cell(const float* __restrict__ Y3,
                                             float* __restrict__ a_st,
                                             float* __restrict__ b_st,
                                             void* __restrict__ outp,
                                             int last) {
  const int col = blockIdx.x;
  const int s = col & (S_ - 1);
  const int b = col >> 11;
  const int lane = threadIdx.x;
  const int f0 = lane * 8;
  const float* d = Y3 + ((long)(3 * b + 0) * S_ + s) * F_ + f0;
  const float* sc = Y3 + ((long)(3 * b + 1) * S_ + s) * F_ + f0;
  const float* sh = Y3 + ((long)(3 * b + 2) * S_ + s) * F_ + f0;
  float* ap = a_st + (long)col * F_ + f0;
  float* bp = b_st + (long)col * F_ + f0;
  const float inv_div = 1.0f / (float)(s + 1);

  const float4 d0 = *(const float4*)d;
  const float4 d1 = *(const float4*)(d + 4);
  const float4 sc0 = *(const float4*)sc;
  const float4 sc1 = *(const float4*)(sc + 4);
  const float4 sh0 = *(const float4*)sh;
  const float4 sh1 = *(const float4*)(sh + 4);

  float c[8];
  c[0] = d0.x;
  c[1] = c[0] + d0.y;
  c[2] = c[1] + d0.z;
  c[3] = c[2] + d0.w;
  c[4] = c[3] + d1.x;
  c[5] = c[4] + d1.y;
  c[6] = c[5] + d1.z;
  c[7] = c[6] + d1.w;
  const float tot = c[7];
  float scan = tot;
#pragma unroll
  for (int off = 1; off < 64; off <<= 1) {
    float nb = __shfl_up(scan, off);
    if (lane >= off) scan += nb;
  }
  const float base = scan - tot;

  float v[8];
  v[0] = (base + c[0]) * inv_div * sc0.x + sh0.x;
  v[1] = (base + c[1]) * inv_div * sc0.y + sh0.y;
  v[2] = (base + c[2]) * inv_div * sc0.z + sh0.z;
  v[3] = (base + c[3]) * inv_div * sc0.w + sh0.w;
  v[4] = (base + c[4]) * inv_div * sc1.x + sh1.x;
  v[5] = (base + c[5]) * inv_div * sc1.y + sh1.y;
  v[6] = (base + c[6]) * inv_div * sc1.z + sh1.z;
  v[7] = (base + c[7]) * inv_div * sc1.w + sh1.w;

  float sum = 0.f, ssq = 0.f;
#pragma unroll
  for (int q = 0; q < 8; ++q) {
    sum += v[q];
    ssq += v[q] * v[q];
  }
#pragma unroll
  for (int off = 1; off < 64; off <<= 1) {
    sum += __shfl_xor(sum, off);
    ssq += __shfl_xor(ssq, off);
  }
  const float mean = sum * (1.0f / (float)F_);
  const float nsq = fmaxf(ssq - (float)F_ * mean * mean, 0.0f);
  const float denom = sqrtf(nsq) * 0.04419417382415922f + 1e-5f;
  const float isc = 0.7071067811865476f / denom;

  const float4 av0 = *(const float4*)ap;
  const float4 av1 = *(const float4*)(ap + 4);
  const float4 bv0 = *(const float4*)bp;
  const float4 bv1 = *(const float4*)(bp + 4);
  float an[8], bn[8];
  const float ai[8] = {av0.x, av0.y, av0.z, av0.w, av1.x, av1.y, av1.z, av1.w};
  const float bi[8] = {bv0.x, bv0.y, bv0.z, bv0.w, bv1.x, bv1.y, bv1.z, bv1.w};
#pragma unroll
  for (int q = 0; q < 8; ++q) {
    const float cell = (v[q] - mean) * isc;
    an[q] = 0.99f * ai[q] + 0.01f * cell;
    bn[q] = bi[q] + an[q];
  }
  *(float4*)ap = {an[0], an[1], an[2], an[3]};
  *(float4*)(ap + 4) = {an[4], an[5], an[6], an[7]};
  *(float4*)bp = {bn[0], bn[1], bn[2], bn[3]};
  *(float4*)(bp + 4) = {bn[4], bn[5], bn[6], bn[7]};
  if (!last) {
    float hv[8];
#pragma unroll
    for (int q = 0; q < 8; ++q) hv[q] = bn[q] + fe_val(f0 + q);
    const int lo = pk4f8(hv[0], hv[1], hv[2], hv[3]);
    const int hi = pk4f8(hv[4], hv[5], hv[6], hv[7]);
    *(int2*)((u8*)outp + (long)col * F_ + f0) = {lo, hi};
  } else {
    bf8 oa, ob;
#pragma unroll
    for (int q = 0; q < 8; ++q) {
      oa[q] = (__bf16)an[q];
      ob[q] = (__bf16)bn[q];
    }
    *(bf8*)((__bf16*)outp + (long)col * (2 * F_) + f0) = oa;
    *(bf8*)((__bf16*)outp + (long)col * (2 * F_) + F_ + f0) = ob;
  }
}

// Fused logits GEMM (bf16) + bias + softmax + NLL. 32-position tiles,
// grid (64, 2) = 128 blocks for 2x parallelism vs R6.
__global__ __launch_bounds__(256) void k_logits_nll(
    const __bf16* __restrict__ A, const __bf16* __restrict__ Bb,
    const float* __restrict__ outb, const int* __restrict__ tgt,
    float* __restrict__ acc) {
  __shared__ __bf16 As[256 * 32];
  __shared__ __bf16 Bs[32 * 32];
  __shared__ float lsm[32 * 256];
  const int tid = threadIdx.x;
  const int b = blockIdx.y;
  const int n0 = blockIdx.x * 32;
  const __bf16* Bt = Bb + (long)b * (S_ * 2 * F_) + (long)n0 * (2 * F_);
  const int lane = tid & 63;
  const int wave = tid >> 6;
  const int l15 = lane & 15;
  const int quad = lane >> 4;
  const int cr = tid >> 2;
  const int csw = (((tid & 3) ^ ((cr >> 1) & 3)) << 3);
  const int roff = ((quad ^ ((l15 >> 1) & 3)) << 3);
  f4 av[4][2] = {};
  for (int k0 = 0; k0 < 2 * F_; k0 += 32) {
#pragma unroll
    for (int i = 0; i < 4; ++i)
      gload_lds16(A + (long)(i * 64 + cr) * (2 * F_) + (k0 + csw),
                  As + ((i * 256 + (wave << 6)) << 3));
    if (wave < 2)
      gload_lds16(Bt + (long)cr * (2 * F_) + (k0 + csw),
                  Bs + ((wave << 6) << 3));
    __syncthreads();
    bf8 af[4], bfr[2];
#pragma unroll
    for (int mt = 0; mt < 4; ++mt)
      af[mt] = *(const bf8*)(As + (wave * 64 + mt * 16 + l15) * 32 + roff);
#pragma unroll
    for (int nt = 0; nt < 2; ++nt)
      bfr[nt] = *(const bf8*)(Bs + (nt * 16 + l15) * 32 + roff);
#pragma unroll
    for (int mt = 0; mt < 4; ++mt)
#pragma unroll
      for (int nt = 0; nt < 2; ++nt)
        av[mt][nt] = __builtin_amdgcn_mfma_f32_16x16x32_bf16(af[mt], bfr[nt],
                                                             av[mt][nt], 0, 0, 0);
    __syncthreads();
  }
#pragma unroll
  for (int mt = 0; mt < 4; ++mt) {
    const int m = wave * 64 + mt * 16 + quad * 4;
#pragma unroll
    for (int nt = 0; nt < 2; ++nt) {
      const int pp = nt * 16 + l15;
      *(f4*)(lsm + pp * C_ + m) = av[mt][nt];
    }
  }
  __syncthreads();
  const float4 bv = *(const float4*)(outb + lane * 4);
  float wsum = 0.f;
  for (int i = 0; i < 8; ++i) {
    const int pp = wave * 8 + i;
    const f4 lv = *(const f4*)(lsm + pp * C_ + lane * 4);
    const float x0 = lv[0] + bv.x, x1 = lv[1] + bv.y, x2 = lv[2] + bv.z,
                x3 = lv[3] + bv.w;
    float mx = fmaxf(fmaxf(x0, x1), fmaxf(x2, x3));
#pragma unroll
    for (int off = 1; off < 64; off <<= 1) mx = fmaxf(mx, __shfl_xor(mx, off));
    float ss = expf(x0 - mx) + expf(x1 - mx) + expf(x2 - mx) + expf(x3 - mx);
#pragma unroll
    for (int off = 1; off < 64; off <<= 1) ss += __shfl_xor(ss, off);
    if (lane == 0) {
      const int t = tgt[b * S_ + n0 + pp];
      wsum += mx + logf(ss) - (lsm[pp * C_ + t] + outb[t]);
    }
  }
  if (lane == 0) atomicAdd(acc, wsum);
}

__global__ void k_final(const float* __restrict__ acc, float* __restrict__ out) {
  out[0] = acc[0] * (1.0f / 4096.0f);
}

extern "C" void kernel_launch(void* const* d_in, const int* in_sizes, int n_in,
                              void* d_out, int out_size, void* d_ws,
                              size_t ws_size, hipStream_t stream) {
  const int* inp = (const int*)d_in[0];
  const int* tgt = (const int*)d_in[1];
  const float* emb = (const float*)d_in[2];
  const float* w0s = (const float*)d_in[3];
  const float* w1s = (const float*)d_in[4];
  const float* w2s = (const float*)d_in[5];
  const float* out_w = (const float*)d_in[6];
  const float* out_b = (const float*)d_in[7];

  char* ws = (char*)d_ws;
  float* acc = (float*)(ws + 0);
  u8* zp = (u8*)(ws + 256);
  float* a_st = (float*)(ws + 4096);
  float* b_st = (float*)(ws + 8392704L);
  u8* h = (u8*)(ws + 16781312L);            // [b*2048+s][512] fp8
  u8* Y1f8 = (u8*)(ws + 20975616L);         // [b][s][3072] fp8
  u8* Y2f8 = (u8*)(ws + 46141440L);         // [b*3+p][s][1024] fp8
  float* Y3 = (float*)(ws + 71307264L);     // [b*3+p][s][512] f32
  u8* W1f8 = (u8*)(ws + 96473088L);         // [(l*3+p)*I+i][3072] fp8 x64
  __bf16* streams = (__bf16*)(ws + 134221824L);
  u8* W0f8 = (u8*)(ws + 146804736L);        // [l][3072][512] fp8 x64
  u8* W2f8 = (u8*)(ws + 153096192L);        // [l][3*512][1024] fp8 x64
  __bf16* OWc = (__bf16*)(ws + 159387648L);

  hipMemsetAsync(ws, 0, 4096, stream);  // acc + zero page
  k_prep<<<12544, 256, 0, stream>>>(w0s, w2s, out_w, w1s, W0f8, W2f8, OWc, W1f8);
  k_embed<<<4096, 64, 0, stream>>>(inp, emb, a_st, b_st, h);

  for (int l = 0; l < 2; ++l) {
    // conv1: (3I x F) @ h -> Y1 fp8, relu
    gemm_f8<1, true, 2, 128, 512, 512><<<dim3(16, 24, 2), 256, 0, stream>>>(
        W0f8 + (long)l * 1572864L, h, Y1f8, zp, 3072, 1, 0L, 0L, 1048576L,
        6291456L);
    // conv2: causal k=3 (I x 3I) -> Y2 fp8, relu
    gemm_f8<3, true, 2, 128, 1024, 3072><<<dim3(16, 8, 6), 256, 0, stream>>>(
        W1f8 + (long)l * 9437184L, Y1f8, Y2f8, zp, 1024, 3, 3145728L, 1024L,
        6291456L, 2097152L);
    // conv3: (F x I) @ Y2 -> Y3 f32
    gemm_f8<1, false, 0, 64, 1024, 1024><<<dim3(32, 4, 6), 256, 0, stream>>>(
        W2f8 + (long)l * 1572864L, Y2f8, Y3, zp, 512, 3, 524288L, 2097152L,
        6291456L, 1048576L);
    k_cell<<<4096, 64, 0, stream>>>(Y3, a_st, b_st,
                                    (l == 0) ? (void*)h : (void*)streams,
                                    (l == 1) ? 1 : 0);
  }

  k_logits_nll<<<dim3(64, 2), 256, 0, stream>>>(OWc, streams, out_b, tgt, acc);
  k_final<<<1, 1, 0, stream>>>(acc, (float*)d_out);
}

// Round 4
// 414.040 us; speedup vs baseline: 2.5345x; 2.5345x over previous
//
#include <hip/hip_runtime.h>

#define S_ 2048
#define F_ 512
#define I_ 1024
#define C_ 256

typedef float f4 __attribute__((ext_vector_type(4)));
typedef __bf16 bf8 __attribute__((ext_vector_type(8)));
typedef __bf16 bf4 __attribute__((ext_vector_type(4)));
typedef int i4v __attribute__((ext_vector_type(4)));
typedef int i8v __attribute__((ext_vector_type(8)));
typedef unsigned char u8;

__device__ __forceinline__ void gload_lds16(const void* g, void* l) {
  __builtin_amdgcn_global_load_lds(
      (const __attribute__((address_space(1))) void*)g,
      (__attribute__((address_space(3))) void*)l, 16, 0, 0);
}

__device__ __forceinline__ float fe_val(int f) {
  const float PI_F = 3.14159265358979323846f;
  float additive = (f & 1) ? 0.0f : 1.0f;
  float fv = ((float)(f + 1) - additive) * 0.5f;
  fv = fv * (8.0f / (float)F_) - logf((float)C_ / (2.0f * PI_F));
  return expf(fv) + additive * PI_F;
}

// MX-fp8 GEMM, R6-measured LDS layout: 128-B rows, 16-B chunk slot s of row r
// holds chunk s ^ (r&7). C[n][m] = (1/64)*sum_k A[m][k]*B'[k][n].
// KW=3 causal: k = t*KD + j, B row (n + t - 2), zero page if < 0.
// OUT: 0 = f32, 2 = fp8-e4m3. Output n-major (ldc = M).
//
// R10 schedule (lessons R7/R8/R9): B double-buffered (2x16KB) + A single
// (16KB) = 48KB <= 53.3KB, so 3 blocks/CU and the balanced 768-grid survive
// (R7's 64KB dbuf broke this). Natural k-order preserved (R8's rotation broke
// L2 tile sharing). All fragments stay in LDS->regs, no address-taken reg
// arrays (R9's spill). Per k-step: stageB(next) fires before compute, so the
// first __syncthreads' vmcnt(0) drain lands after the MFMA cluster; only the
// 16KB A-stage stays exposed at the second barrier (~half of R6's stall).
template <int KW, bool RELU, int OUT, int NTILE, int KD, int LDB>
__global__ __launch_bounds__(256) void gemm_f8(
    const u8* __restrict__ Ab, const u8* __restrict__ Bb, void* __restrict__ Cb,
    const u8* __restrict__ zpage, int M, int PZ, long sAp, long sBp, long sBb,
    long sCz) {
  constexpr int NF = NTILE / 32;  // n-frags per wave
  constexpr int NIT = KD / 128;   // 128-byte k-steps per segment
  constexpr int AK = KW * KD;     // A row stride
  constexpr int BP = NTILE / 32;  // B staging passes (32 rows each)
  constexpr int NSTEP = KW * NIT;
  static_assert(NSTEP % 2 == 0, "even k-step count required");
  __shared__ u8 Asm[128 * 128];
  __shared__ u8 Bsm[2][NTILE * 128];
  const int tid = threadIdx.x;
  const int z = blockIdx.z;
  const int p = z % PZ;
  const int bb = z / PZ;
  const u8* A = Ab + (long)p * sAp;
  const u8* B = Bb + (long)bb * sBb + (long)p * sBp;
  const int m0 = blockIdx.y * 128;
  const int n0 = blockIdx.x * NTILE;
  const int lane = tid & 63;
  const int wave = tid >> 6;
  const int wr = wave >> 1;
  const int wc = wave & 1;
  const int l15 = lane & 15;
  const int quad = lane >> 4;
  const int cr = tid >> 3;                        // staged row within pass
  const int csw = (((tid & 7) ^ (cr & 7)) << 4);  // fetched chunk
  const int off0 = (((2 * quad) ^ (l15 & 7)) << 4);
  const int off1 = (((2 * quad + 1) ^ (l15 & 7)) << 4);
  f4 acc[4][NF] = {};

  auto stageA = [&](int ks) {
    const int t = (KW == 1) ? 0 : (ks / NIT);
    const int kb = (ks & (NIT - 1)) * 128;
    const u8* pA = A + (long)t * KD + kb;
#pragma unroll
    for (int g = 0; g < 4; ++g)
      gload_lds16(pA + (long)(m0 + g * 32 + cr) * AK + csw,
                  Asm + g * 4096 + wave * 1024);
  };

  auto stageB = [&](int ks, int buf) {
    const int t = (KW == 1) ? 0 : (ks / NIT);
    const int kb = (ks & (NIT - 1)) * 128;
#pragma unroll
    for (int g = 0; g < BP; ++g) {
      const int rg = n0 + g * 32 + cr + ((KW == 3) ? (t - 2) : 0);
      const u8* pB = (KW == 3 && rg < 0) ? (zpage + csw)
                                         : (B + (long)rg * LDB + kb + csw);
      gload_lds16(pB, &Bsm[buf][g * 4096 + wave * 1024]);
    }
  };

  // ds_read fragments (transient locals, fully unrolled — stays in VGPRs)
  // + MFMA cluster under setprio.
  auto compute = [&](int buf) {
    i8v af[4], bfr[NF];
#pragma unroll
    for (int mt = 0; mt < 4; ++mt) {
      const u8* rp = Asm + (wr * 64 + mt * 16 + l15) * 128;
      const i4v lo = *(const i4v*)(rp + off0);
      const i4v hi = *(const i4v*)(rp + off1);
      af[mt][0] = lo[0]; af[mt][1] = lo[1]; af[mt][2] = lo[2]; af[mt][3] = lo[3];
      af[mt][4] = hi[0]; af[mt][5] = hi[1]; af[mt][6] = hi[2]; af[mt][7] = hi[3];
    }
#pragma unroll
    for (int nt = 0; nt < NF; ++nt) {
      const u8* rp = &Bsm[buf][(wc * (NTILE / 2) + nt * 16 + l15) * 128];
      const i4v lo = *(const i4v*)(rp + off0);
      const i4v hi = *(const i4v*)(rp + off1);
      bfr[nt][0] = lo[0]; bfr[nt][1] = lo[1]; bfr[nt][2] = lo[2]; bfr[nt][3] = lo[3];
      bfr[nt][4] = hi[0]; bfr[nt][5] = hi[1]; bfr[nt][6] = hi[2]; bfr[nt][7] = hi[3];
    }
    __builtin_amdgcn_s_setprio(1);
#pragma unroll
    for (int mt = 0; mt < 4; ++mt)
#pragma unroll
      for (int nt = 0; nt < NF; ++nt)
        acc[mt][nt] = __builtin_amdgcn_mfma_scale_f32_16x16x128_f8f6f4(
            af[mt], bfr[nt], acc[mt][nt], 0, 0, 0, 0x7F7F7F7F, 0, 0x7F7F7F7F);
    __builtin_amdgcn_s_setprio(0);
  };

  stageA(0);
  stageB(0, 0);
  __syncthreads();
#pragma unroll 1
  for (int ks = 0; ks < NSTEP; ks += 2) {
    stageB(ks + 1, 1);   // prefetch next B under compute
    compute(0);
    __syncthreads();     // drains B(ks+1); Asm reads done by all waves
    stageA(ks + 1);      // only A (16KB) exposed here
    __syncthreads();
    if (ks + 2 < NSTEP) stageB(ks + 2, 0);
    compute(1);
    if (ks + 2 < NSTEP) {
      __syncthreads();
      stageA(ks + 2);
      __syncthreads();
    }
  }

#pragma unroll
  for (int mt = 0; mt < 4; ++mt) {
    const int m = m0 + wr * 64 + mt * 16 + quad * 4;
#pragma unroll
    for (int nt = 0; nt < NF; ++nt) {
      const int n = n0 + wc * (NTILE / 2) + nt * 16 + l15;
      f4 v = acc[mt][nt];
#pragma unroll
      for (int q = 0; q < 4; ++q) {
        v[q] *= 0.015625f;  // undo weight x64
        if (RELU) v[q] = fmaxf(v[q], 0.0f);
      }
      if (OUT == 2) {
        int r = __builtin_amdgcn_cvt_pk_fp8_f32(v[0], v[1], 0, false);
        r = __builtin_amdgcn_cvt_pk_fp8_f32(v[2], v[3], r, true);
        *(int*)((u8*)Cb + (long)z * sCz + (long)n * M + m) = r;
      } else {
        *(f4*)((float*)Cb + (long)z * sCz + (long)n * M + m) = v;
      }
    }
  }
}

__device__ __forceinline__ void cvt4(const float* __restrict__ s,
                                     __bf16* __restrict__ d, long T) {
  const long i = T * 4;
  const float4 v = *(const float4*)(s + i);
  bf4 o;
  o[0] = (__bf16)v.x;
  o[1] = (__bf16)v.y;
  o[2] = (__bf16)v.z;
  o[3] = (__bf16)v.w;
  *(bf4*)(d + i) = o;
}

__device__ __forceinline__ void cvt4f8(const float* __restrict__ s,
                                       u8* __restrict__ d, long T) {
  const long i = T * 4;
  const float4 v = *(const float4*)(s + i);
  int r = __builtin_amdgcn_cvt_pk_fp8_f32(v.x * 64.0f, v.y * 64.0f, 0, false);
  r = __builtin_amdgcn_cvt_pk_fp8_f32(v.z * 64.0f, v.w * 64.0f, r, true);
  *(int*)(d + i) = r;
}

__device__ __forceinline__ int pk4f8(float a, float b, float c, float d) {
  int r = __builtin_amdgcn_cvt_pk_fp8_f32(a, b, 0, false);
  return __builtin_amdgcn_cvt_pk_fp8_f32(c, d, r, true);
}

// One dispatch: w0s/w2s -> fp8 x64, out_w -> bf16, w1s reorder -> fp8 x64.
// w1 path vectorized: thread handles 4 j's (3 float4 reads, 3 int stores).
__global__ void k_prep(const float* __restrict__ w0, const float* __restrict__ w2,
                       const float* __restrict__ ow, const float* __restrict__ w1,
                       u8* __restrict__ W0f8, u8* __restrict__ W2f8,
                       __bf16* __restrict__ OWc, u8* __restrict__ W1f8) {
  long T = (long)blockIdx.x * 256 + threadIdx.x;
  if (T < 786432L) {
    cvt4f8(w0, W0f8, T);
    return;
  }
  T -= 786432L;
  if (T < 786432L) {
    cvt4f8(w2, W2f8, T);
    return;
  }
  T -= 786432L;
  if (T < 65536L) {
    cvt4(ow, OWc, T);
    return;
  }
  T -= 65536L;
  // w1s (L,3,I,I,K=3) -> W1f8[(l*3+p)*I+i][t*1024 + j], value x64
  const long j4 = T & 255;   // group of 4 j's
  const long r3 = T >> 8;
  const float* src = w1 + r3 * 3072 + j4 * 12;
  const float4 v0 = *(const float4*)src;       // j0t0 j0t1 j0t2 j1t0
  const float4 v1 = *(const float4*)(src + 4); // j1t1 j1t2 j2t0 j2t1
  const float4 v2 = *(const float4*)(src + 8); // j2t2 j3t0 j3t1 j3t2
  u8* dst = W1f8 + r3 * 3072 + j4 * 4;
  *(int*)(dst) = pk4f8(v0.x * 64.f, v0.w * 64.f, v1.z * 64.f, v2.y * 64.f);
  *(int*)(dst + 1024) = pk4f8(v0.y * 64.f, v1.x * 64.f, v1.w * 64.f, v2.z * 64.f);
  *(int*)(dst + 2048) = pk4f8(v0.z * 64.f, v1.y * 64.f, v2.x * 64.f, v2.w * 64.f);
}

// One wave per (b,s): gather embedding -> a/b state (f32) + layer-0 h (fp8).
__global__ __launch_bounds__(64) void k_embed(const int* __restrict__ inp,
                                              const float* __restrict__ emb,
                                              float* __restrict__ a_st,
                                              float* __restrict__ b_st,
                                              u8* __restrict__ h) {
  const int col = blockIdx.x;
  const int lane = threadIdx.x;
  const int f0 = lane * 8;
  const float* e = emb + (long)inp[col] * (2 * F_);
  const float4 a0 = *(const float4*)(e + f0);
  const float4 a1 = *(const float4*)(e + f0 + 4);
  const float4 b0 = *(const float4*)(e + F_ + f0);
  const float4 b1 = *(const float4*)(e + F_ + f0 + 4);
  *(float4*)(a_st + (long)col * F_ + f0) = a0;
  *(float4*)(a_st + (long)col * F_ + f0 + 4) = a1;
  *(float4*)(b_st + (long)col * F_ + f0) = b0;
  *(float4*)(b_st + (long)col * F_ + f0 + 4) = b1;
  const float bb[8] = {b0.x, b0.y, b0.z, b0.w, b1.x, b1.y, b1.z, b1.w};
  float hv[8];
#pragma unroll
  for (int q = 0; q < 8; ++q) hv[q] = bb[q] + fe_val(f0 + q);
  const int lo = pk4f8(hv[0], hv[1], hv[2], hv[3]);
  const int hi = pk4f8(hv[4], hv[5], hv[6], hv[7]);
  *(int2*)(h + (long)col * F_ + f0) = {lo, hi};
}

// One wave per (b,s) column: shfl-scan cumsum, stats, EMA; fuse next h (fp8)
// or final streams (bf16).
__global__ __launch_bounds__(64) void k_cell(const float* __restrict__ Y3,
                                             float* __restrict__ a_st,
                                             float* __restrict__ b_st,
                                             void* __restrict__ outp,
                                             int last) {
  const int col = blockIdx.x;
  const int s = col & (S_ - 1);
  const int b = col >> 11;
  const int lane = threadIdx.x;
  const int f0 = lane * 8;
  const float* d = Y3 + ((long)(3 * b + 0) * S_ + s) * F_ + f0;
  const float* sc = Y3 + ((long)(3 * b + 1) * S_ + s) * F_ + f0;
  const float* sh = Y3 + ((long)(3 * b + 2) * S_ + s) * F_ + f0;
  float* ap = a_st + (long)col * F_ + f0;
  float* bp = b_st + (long)col * F_ + f0;
  const float inv_div = 1.0f / (float)(s + 1);

  const float4 d0 = *(const float4*)d;
  const float4 d1 = *(const float4*)(d + 4);
  const float4 sc0 = *(const float4*)sc;
  const float4 sc1 = *(const float4*)(sc + 4);
  const float4 sh0 = *(const float4*)sh;
  const float4 sh1 = *(const float4*)(sh + 4);

  float c[8];
  c[0] = d0.x;
  c[1] = c[0] + d0.y;
  c[2] = c[1] + d0.z;
  c[3] = c[2] + d0.w;
  c[4] = c[3] + d1.x;
  c[5] = c[4] + d1.y;
  c[6] = c[5] + d1.z;
  c[7] = c[6] + d1.w;
  const float tot = c[7];
  float scan = tot;
#pragma unroll
  for (int off = 1; off < 64; off <<= 1) {
    float nb = __shfl_up(scan, off);
    if (lane >= off) scan += nb;
  }
  const float base = scan - tot;

  float v[8];
  v[0] = (base + c[0]) * inv_div * sc0.x + sh0.x;
  v[1] = (base + c[1]) * inv_div * sc0.y + sh0.y;
  v[2] = (base + c[2]) * inv_div * sc0.z + sh0.z;
  v[3] = (base + c[3]) * inv_div * sc0.w + sh0.w;
  v[4] = (base + c[4]) * inv_div * sc1.x + sh1.x;
  v[5] = (base + c[5]) * inv_div * sc1.y + sh1.y;
  v[6] = (base + c[6]) * inv_div * sc1.z + sh1.z;
  v[7] = (base + c[7]) * inv_div * sc1.w + sh1.w;

  float sum = 0.f, ssq = 0.f;
#pragma unroll
  for (int q = 0; q < 8; ++q) {
    sum += v[q];
    ssq += v[q] * v[q];
  }
#pragma unroll
  for (int off = 1; off < 64; off <<= 1) {
    sum += __shfl_xor(sum, off);
    ssq += __shfl_xor(ssq, off);
  }
  const float mean = sum * (1.0f / (float)F_);
  const float nsq = fmaxf(ssq - (float)F_ * mean * mean, 0.0f);
  const float denom = sqrtf(nsq) * 0.04419417382415922f + 1e-5f;
  const float isc = 0.7071067811865476f / denom;

  const float4 av0 = *(const float4*)ap;
  const float4 av1 = *(const float4*)(ap + 4);
  const float4 bv0 = *(const float4*)bp;
  const float4 bv1 = *(const float4*)(bp + 4);
  float an[8], bn[8];
  const float ai[8] = {av0.x, av0.y, av0.z, av0.w, av1.x, av1.y, av1.z, av1.w};
  const float bi[8] = {bv0.x, bv0.y, bv0.z, bv0.w, bv1.x, bv1.y, bv1.z, bv1.w};
#pragma unroll
  for (int q = 0; q < 8; ++q) {
    const float cell = (v[q] - mean) * isc;
    an[q] = 0.99f * ai[q] + 0.01f * cell;
    bn[q] = bi[q] + an[q];
  }
  *(float4*)ap = {an[0], an[1], an[2], an[3]};
  *(float4*)(ap + 4) = {an[4], an[5], an[6], an[7]};
  *(float4*)bp = {bn[0], bn[1], bn[2], bn[3]};
  *(float4*)(bp + 4) = {bn[4], bn[5], bn[6], bn[7]};
  if (!last) {
    float hv[8];
#pragma unroll
    for (int q = 0; q < 8; ++q) hv[q] = bn[q] + fe_val(f0 + q);
    const int lo = pk4f8(hv[0], hv[1], hv[2], hv[3]);
    const int hi = pk4f8(hv[4], hv[5], hv[6], hv[7]);
    *(int2*)((u8*)outp + (long)col * F_ + f0) = {lo, hi};
  } else {
    bf8 oa, ob;
#pragma unroll
    for (int q = 0; q < 8; ++q) {
      oa[q] = (__bf16)an[q];
      ob[q] = (__bf16)bn[q];
    }
    *(bf8*)((__bf16*)outp + (long)col * (2 * F_) + f0) = oa;
    *(bf8*)((__bf16*)outp + (long)col * (2 * F_) + F_ + f0) = ob;
  }
}

// Fused logits GEMM (bf16) + bias + softmax + NLL. 32-position tiles,
// grid (64, 2) = 128 blocks for 2x parallelism vs R6.
__global__ __launch_bounds__(256) void k_logits_nll(
    const __bf16* __restrict__ A, const __bf16* __restrict__ Bb,
    const float* __restrict__ outb, const int* __restrict__ tgt,
    float* __restrict__ acc) {
  __shared__ __bf16 As[256 * 32];
  __shared__ __bf16 Bs[32 * 32];
  __shared__ float lsm[32 * 256];
  const int tid = threadIdx.x;
  const int b = blockIdx.y;
  const int n0 = blockIdx.x * 32;
  const __bf16* Bt = Bb + (long)b * (S_ * 2 * F_) + (long)n0 * (2 * F_);
  const int lane = tid & 63;
  const int wave = tid >> 6;
  const int l15 = lane & 15;
  const int quad = lane >> 4;
  const int cr = tid >> 2;
  const int csw = (((tid & 3) ^ ((cr >> 1) & 3)) << 3);
  const int roff = ((quad ^ ((l15 >> 1) & 3)) << 3);
  f4 av[4][2] = {};
  for (int k0 = 0; k0 < 2 * F_; k0 += 32) {
#pragma unroll
    for (int i = 0; i < 4; ++i)
      gload_lds16(A + (long)(i * 64 + cr) * (2 * F_) + (k0 + csw),
                  As + ((i * 256 + (wave << 6)) << 3));
    if (wave < 2)
      gload_lds16(Bt + (long)cr * (2 * F_) + (k0 + csw),
                  Bs + ((wave << 6) << 3));
    __syncthreads();
    bf8 af[4], bfr[2];
#pragma unroll
    for (int mt = 0; mt < 4; ++mt)
      af[mt] = *(const bf8*)(As + (wave * 64 + mt * 16 + l15) * 32 + roff);
#pragma unroll
    for (int nt = 0; nt < 2; ++nt)
      bfr[nt] = *(const bf8*)(Bs + (nt * 16 + l15) * 32 + roff);
#pragma unroll
    for (int mt = 0; mt < 4; ++mt)
#pragma unroll
      for (int nt = 0; nt < 2; ++nt)
        av[mt][nt] = __builtin_amdgcn_mfma_f32_16x16x32_bf16(af[mt], bfr[nt],
                                                             av[mt][nt], 0, 0, 0);
    __syncthreads();
  }
#pragma unroll
  for (int mt = 0; mt < 4; ++mt) {
    const int m = wave * 64 + mt * 16 + quad * 4;
#pragma unroll
    for (int nt = 0; nt < 2; ++nt) {
      const int pp = nt * 16 + l15;
      *(f4*)(lsm + pp * C_ + m) = av[mt][nt];
    }
  }
  __syncthreads();
  const float4 bv = *(const float4*)(outb + lane * 4);
  float wsum = 0.f;
  for (int i = 0; i < 8; ++i) {
    const int pp = wave * 8 + i;
    const f4 lv = *(const f4*)(lsm + pp * C_ + lane * 4);
    const float x0 = lv[0] + bv.x, x1 = lv[1] + bv.y, x2 = lv[2] + bv.z,
                x3 = lv[3] + bv.w;
    float mx = fmaxf(fmaxf(x0, x1), fmaxf(x2, x3));
#pragma unroll
    for (int off = 1; off < 64; off <<= 1) mx = fmaxf(mx, __shfl_xor(mx, off));
    float ss = expf(x0 - mx) + expf(x1 - mx) + expf(x2 - mx) + expf(x3 - mx);
#pragma unroll
    for (int off = 1; off < 64; off <<= 1) ss += __shfl_xor(ss, off);
    if (lane == 0) {
      const int t = tgt[b * S_ + n0 + pp];
      wsum += mx + logf(ss) - (lsm[pp * C_ + t] + outb[t]);
    }
  }
  if (lane == 0) atomicAdd(acc, wsum);
}

__global__ void k_final(const float* __restrict__ acc, float* __restrict__ out) {
  out[0] = acc[0] * (1.0f / 4096.0f);
}

extern "C" void kernel_launch(void* const* d_in, const int* in_sizes, int n_in,
                              void* d_out, int out_size, void* d_ws,
                              size_t ws_size, hipStream_t stream) {
  const int* inp = (const int*)d_in[0];
  const int* tgt = (const int*)d_in[1];
  const float* emb = (const float*)d_in[2];
  const float* w0s = (const float*)d_in[3];
  const float* w1s = (const float*)d_in[4];
  const float* w2s = (const float*)d_in[5];
  const float* out_w = (const float*)d_in[6];
  const float* out_b = (const float*)d_in[7];

  char* ws = (char*)d_ws;
  float* acc = (float*)(ws + 0);
  u8* zp = (u8*)(ws + 256);
  float* a_st = (float*)(ws + 4096);
  float* b_st = (float*)(ws + 8392704L);
  u8* h = (u8*)(ws + 16781312L);            // [b*2048+s][512] fp8
  u8* Y1f8 = (u8*)(ws + 20975616L);         // [b][s][3072] fp8
  u8* Y2f8 = (u8*)(ws + 46141440L);         // [b*3+p][s][1024] fp8
  float* Y3 = (float*)(ws + 71307264L);     // [b*3+p][s][512] f32
  u8* W1f8 = (u8*)(ws + 96473088L);         // [(l*3+p)*I+i][3072] fp8 x64
  __bf16* streams = (__bf16*)(ws + 134221824L);
  u8* W0f8 = (u8*)(ws + 146804736L);        // [l][3072][512] fp8 x64
  u8* W2f8 = (u8*)(ws + 153096192L);        // [l][3*512][1024] fp8 x64
  __bf16* OWc = (__bf16*)(ws + 159387648L);

  hipMemsetAsync(ws, 0, 4096, stream);  // acc + zero page
  k_prep<<<12544, 256, 0, stream>>>(w0s, w2s, out_w, w1s, W0f8, W2f8, OWc, W1f8);
  k_embed<<<4096, 64, 0, stream>>>(inp, emb, a_st, b_st, h);

  for (int l = 0; l < 2; ++l) {
    // conv1: (3I x F) @ h -> Y1 fp8, relu
    gemm_f8<1, true, 2, 128, 512, 512><<<dim3(16, 24, 2), 256, 0, stream>>>(
        W0f8 + (long)l * 1572864L, h, Y1f8, zp, 3072, 1, 0L, 0L, 1048576L,
        6291456L);
    // conv2: causal k=3 (I x 3I) -> Y2 fp8, relu
    gemm_f8<3, true, 2, 128, 1024, 3072><<<dim3(16, 8, 6), 256, 0, stream>>>(
        W1f8 + (long)l * 9437184L, Y1f8, Y2f8, zp, 1024, 3, 3145728L, 1024L,
        6291456L, 2097152L);
    // conv3: (F x I) @ Y2 -> Y3 f32
    gemm_f8<1, false, 0, 64, 1024, 1024><<<dim3(32, 4, 6), 256, 0, stream>>>(
        W2f8 + (long)l * 1572864L, Y2f8, Y3, zp, 512, 3, 524288L, 2097152L,
        6291456L, 1048576L);
    k_cell<<<4096, 64, 0, stream>>>(Y3, a_st, b_st,
                                    (l == 0) ? (void*)h : (void*)streams,
                                    (l == 1) ? 1 : 0);
  }

  k_logits_nll<<<dim3(64, 2), 256, 0, stream>>>(OWc, streams, out_b, tgt, acc);
  k_final<<<1, 1, 0, stream>>>(acc, (float*)d_out);
}

// Round 5
// 376.309 us; speedup vs baseline: 2.7887x; 1.1003x over previous
//
#include <hip/hip_runtime.h>

#define S_ 2048
#define F_ 512
#define I_ 1024
#define C_ 256

typedef float f4 __attribute__((ext_vector_type(4)));
typedef __bf16 bf8 __attribute__((ext_vector_type(8)));
typedef __bf16 bf4 __attribute__((ext_vector_type(4)));
typedef int i4v __attribute__((ext_vector_type(4)));
typedef int i8v __attribute__((ext_vector_type(8)));
typedef unsigned char u8;

__device__ __forceinline__ void gload_lds16(const void* g, void* l) {
  __builtin_amdgcn_global_load_lds(
      (const __attribute__((address_space(1))) void*)g,
      (__attribute__((address_space(3))) void*)l, 16, 0, 0);
}

__device__ __forceinline__ float fe_val(int f) {
  const float PI_F = 3.14159265358979323846f;
  float additive = (f & 1) ? 0.0f : 1.0f;
  float fv = ((float)(f + 1) - additive) * 0.5f;
  fv = fv * (8.0f / (float)F_) - logf((float)C_ / (2.0f * PI_F));
  return expf(fv) + additive * PI_F;
}

// MX-fp8 GEMM, R6-measured LDS layout: 128-B rows, 16-B chunk slot s of row r
// holds chunk s ^ (r&7). C[n][m] = (1/64)*sum_k A[m][k]*B'[k][n].
// KW=3 causal: k = t*KD + j, B row (n + t - 2), zero page if < 0.
// OUT: 0 = f32, 2 = fp8-e4m3. Output n-major (ldc = M).
//
// R11: constraints pinned by R7-R10 failures: LDS must stay <= 32KB (48KB+
// drops to 2 blocks/CU: R10 occupancy 17%), natural k-order (R8 rotation cost
// +75% FETCH), no address-taken reg arrays (R9 spill), single-buffer 2-barrier
// schedule (verified). New: for KW==3 (conv2), kb-outer/t-inner order with a
// CYCLIC 128-row B buffer — B is staged once per kb (plus 2 single halo rows)
// instead of 3x, since t=0,1,2 read the same rows shifted by 1. Cyclic row
// H=(grow+2-n0)&127 preserves the row&7 swizzle key (128 = 0 mod 8). t=1,2
// k-steps stage only A (4 loads) + 1 halo row -> shorter vmcnt drains.
template <int KW, bool RELU, int OUT, int NTILE, int KD, int LDB>
__global__ __launch_bounds__(256) void gemm_f8(
    const u8* __restrict__ Ab, const u8* __restrict__ Bb, void* __restrict__ Cb,
    const u8* __restrict__ zpage, int M, int PZ, long sAp, long sBp, long sBb,
    long sCz) {
  constexpr int NF = NTILE / 32;  // n-frags per wave
  constexpr int NIT = KD / 128;   // 128-byte k-steps per segment
  constexpr int AK = KW * KD;     // A row stride
  constexpr int BP = NTILE / 32;  // B staging passes (32 rows each)
  constexpr int NSTEP = KW * NIT;
  __shared__ u8 Asm[128 * 128];
  __shared__ u8 Bsm[NTILE * 128];
  const int tid = threadIdx.x;
  const int z = blockIdx.z;
  const int p = z % PZ;
  const int bb = z / PZ;
  const u8* A = Ab + (long)p * sAp;
  const u8* B = Bb + (long)bb * sBb + (long)p * sBp;
  const int m0 = blockIdx.y * 128;
  const int n0 = blockIdx.x * NTILE;
  const int lane = tid & 63;
  const int wave = tid >> 6;
  const int wr = wave >> 1;
  const int wc = wave & 1;
  const int l15 = lane & 15;
  const int quad = lane >> 4;
  const int cr = tid >> 3;                        // staged row within pass
  const int csw = (((tid & 7) ^ (cr & 7)) << 4);  // fetched chunk
  const int off0 = (((2 * quad) ^ (l15 & 7)) << 4);
  const int off1 = (((2 * quad + 1) ^ (l15 & 7)) << 4);
  f4 acc[4][NF] = {};

  // Stage A k-slice (t, kb) into Asm (16 KB, 4 loads/thread).
  auto stageA = [&](int t, int kb) {
    const u8* pA = A + (long)t * KD + kb * 128;
#pragma unroll
    for (int g = 0; g < 4; ++g)
      gload_lds16(pA + (long)(m0 + g * 32 + cr) * AK + csw,
                  Asm + g * 4096 + wave * 1024);
  };

  // Stage full B k-slice (rows n0 + t - 2 ..) into Bsm (R6 layout).
  auto stageBfull = [&](int t, int kb) {
#pragma unroll
    for (int g = 0; g < BP; ++g) {
      const int rg = n0 + g * 32 + cr + ((KW == 3) ? (t - 2) : 0);
      const u8* pB = (KW == 3 && rg < 0) ? (zpage + csw)
                                         : (B + (long)rg * LDB + kb * 128 + csw);
      gload_lds16(pB, Bsm + g * 4096 + wave * 1024);
    }
  };

  // Stage ONE halo row (global row n0+126+hrow) into cyclic LDS row hrow.
  // Swizzle key = hrow & 7 = hrow; lane l fetches chunk l ^ hrow into slot l.
  auto stageBrow = [&](int hrow, int kb) {
    if (wave == 0 && lane < 8) {
      const u8* pB =
          B + (long)(n0 + 126 + hrow) * LDB + kb * 128 + ((lane ^ hrow) << 4);
      gload_lds16(pB, Bsm + hrow * 128);
    }
  };

  // ds_read fragments + MFMA cluster. B rows shifted by tshift in the cyclic
  // buffer: row (base+tshift)&127, swizzle key (l15+tshift)&7. tshift=0
  // reproduces the R6 read exactly.
  auto computeB = [&](int tshift) {
    i8v af[4], bfr[NF];
#pragma unroll
    for (int mt = 0; mt < 4; ++mt) {
      const u8* rp = Asm + (wr * 64 + mt * 16 + l15) * 128;
      const i4v lo = *(const i4v*)(rp + off0);
      const i4v hi = *(const i4v*)(rp + off1);
      af[mt][0] = lo[0]; af[mt][1] = lo[1]; af[mt][2] = lo[2]; af[mt][3] = lo[3];
      af[mt][4] = hi[0]; af[mt][5] = hi[1]; af[mt][6] = hi[2]; af[mt][7] = hi[3];
    }
    const int bkey = ((l15 + tshift) & 7);
    const int bo0 = (((2 * quad) ^ bkey) << 4);
    const int bo1 = (((2 * quad + 1) ^ bkey) << 4);
#pragma unroll
    for (int nt = 0; nt < NF; ++nt) {
      const int hr = (wc * (NTILE / 2) + nt * 16 + l15 + tshift) & (NTILE - 1);
      const u8* rp = Bsm + hr * 128;
      const i4v lo = *(const i4v*)(rp + bo0);
      const i4v hi = *(const i4v*)(rp + bo1);
      bfr[nt][0] = lo[0]; bfr[nt][1] = lo[1]; bfr[nt][2] = lo[2]; bfr[nt][3] = lo[3];
      bfr[nt][4] = hi[0]; bfr[nt][5] = hi[1]; bfr[nt][6] = hi[2]; bfr[nt][7] = hi[3];
    }
#pragma unroll
    for (int mt = 0; mt < 4; ++mt)
#pragma unroll
      for (int nt = 0; nt < NF; ++nt)
        acc[mt][nt] = __builtin_amdgcn_mfma_scale_f32_16x16x128_f8f6f4(
            af[mt], bfr[nt], acc[mt][nt], 0, 0, 0, 0x7F7F7F7F, 0, 0x7F7F7F7F);
  };

  if constexpr (KW == 1) {
    // R6 schedule verbatim.
#pragma unroll 1
    for (int ks = 0; ks < NSTEP; ++ks) {
      stageA(0, ks);
      stageBfull(0, ks);
      __syncthreads();
      computeB(0);
      __syncthreads();
    }
  } else {
    // kb-outer / t-inner, cyclic B halo.
#pragma unroll 1
    for (int kb = 0; kb < NIT; ++kb) {
      stageA(0, kb);
      stageBfull(0, kb);  // rows n0-2 .. n0+125 -> LDS rows 0..127
      __syncthreads();
      computeB(0);
      __syncthreads();
      stageA(1, kb);
      stageBrow(0, kb);  // row n0+126 -> LDS row 0 (overwrites n0-2: done)
      __syncthreads();
      computeB(1);
      __syncthreads();
      stageA(2, kb);
      stageBrow(1, kb);  // row n0+127 -> LDS row 1 (overwrites n0-1: done)
      __syncthreads();
      computeB(2);
      __syncthreads();
    }
  }

#pragma unroll
  for (int mt = 0; mt < 4; ++mt) {
    const int m = m0 + wr * 64 + mt * 16 + quad * 4;
#pragma unroll
    for (int nt = 0; nt < NF; ++nt) {
      const int n = n0 + wc * (NTILE / 2) + nt * 16 + l15;
      f4 v = acc[mt][nt];
#pragma unroll
      for (int q = 0; q < 4; ++q) {
        v[q] *= 0.015625f;  // undo weight x64
        if (RELU) v[q] = fmaxf(v[q], 0.0f);
      }
      if (OUT == 2) {
        int r = __builtin_amdgcn_cvt_pk_fp8_f32(v[0], v[1], 0, false);
        r = __builtin_amdgcn_cvt_pk_fp8_f32(v[2], v[3], r, true);
        *(int*)((u8*)Cb + (long)z * sCz + (long)n * M + m) = r;
      } else {
        *(f4*)((float*)Cb + (long)z * sCz + (long)n * M + m) = v;
      }
    }
  }
}

__device__ __forceinline__ void cvt4(const float* __restrict__ s,
                                     __bf16* __restrict__ d, long T) {
  const long i = T * 4;
  const float4 v = *(const float4*)(s + i);
  bf4 o;
  o[0] = (__bf16)v.x;
  o[1] = (__bf16)v.y;
  o[2] = (__bf16)v.z;
  o[3] = (__bf16)v.w;
  *(bf4*)(d + i) = o;
}

__device__ __forceinline__ void cvt4f8(const float* __restrict__ s,
                                       u8* __restrict__ d, long T) {
  const long i = T * 4;
  const float4 v = *(const float4*)(s + i);
  int r = __builtin_amdgcn_cvt_pk_fp8_f32(v.x * 64.0f, v.y * 64.0f, 0, false);
  r = __builtin_amdgcn_cvt_pk_fp8_f32(v.z * 64.0f, v.w * 64.0f, r, true);
  *(int*)(d + i) = r;
}

__device__ __forceinline__ int pk4f8(float a, float b, float c, float d) {
  int r = __builtin_amdgcn_cvt_pk_fp8_f32(a, b, 0, false);
  return __builtin_amdgcn_cvt_pk_fp8_f32(c, d, r, true);
}

// One dispatch: w0s/w2s -> fp8 x64, out_w -> bf16, w1s reorder -> fp8 x64.
// w1 path vectorized: thread handles 4 j's (3 float4 reads, 3 int stores).
__global__ void k_prep(const float* __restrict__ w0, const float* __restrict__ w2,
                       const float* __restrict__ ow, const float* __restrict__ w1,
                       u8* __restrict__ W0f8, u8* __restrict__ W2f8,
                       __bf16* __restrict__ OWc, u8* __restrict__ W1f8) {
  long T = (long)blockIdx.x * 256 + threadIdx.x;
  if (T < 786432L) {
    cvt4f8(w0, W0f8, T);
    return;
  }
  T -= 786432L;
  if (T < 786432L) {
    cvt4f8(w2, W2f8, T);
    return;
  }
  T -= 786432L;
  if (T < 65536L) {
    cvt4(ow, OWc, T);
    return;
  }
  T -= 65536L;
  // w1s (L,3,I,I,K=3) -> W1f8[(l*3+p)*I+i][t*1024 + j], value x64
  const long j4 = T & 255;   // group of 4 j's
  const long r3 = T >> 8;
  const float* src = w1 + r3 * 3072 + j4 * 12;
  const float4 v0 = *(const float4*)src;       // j0t0 j0t1 j0t2 j1t0
  const float4 v1 = *(const float4*)(src + 4); // j1t1 j1t2 j2t0 j2t1
  const float4 v2 = *(const float4*)(src + 8); // j2t2 j3t0 j3t1 j3t2
  u8* dst = W1f8 + r3 * 3072 + j4 * 4;
  *(int*)(dst) = pk4f8(v0.x * 64.f, v0.w * 64.f, v1.z * 64.f, v2.y * 64.f);
  *(int*)(dst + 1024) = pk4f8(v0.y * 64.f, v1.x * 64.f, v1.w * 64.f, v2.z * 64.f);
  *(int*)(dst + 2048) = pk4f8(v0.z * 64.f, v1.y * 64.f, v2.x * 64.f, v2.w * 64.f);
}

// One wave per (b,s): gather embedding -> a/b state (f32) + layer-0 h (fp8).
__global__ __launch_bounds__(64) void k_embed(const int* __restrict__ inp,
                                              const float* __restrict__ emb,
                                              float* __restrict__ a_st,
                                              float* __restrict__ b_st,
                                              u8* __restrict__ h) {
  const int col = blockIdx.x;
  const int lane = threadIdx.x;
  const int f0 = lane * 8;
  const float* e = emb + (long)inp[col] * (2 * F_);
  const float4 a0 = *(const float4*)(e + f0);
  const float4 a1 = *(const float4*)(e + f0 + 4);
  const float4 b0 = *(const float4*)(e + F_ + f0);
  const float4 b1 = *(const float4*)(e + F_ + f0 + 4);
  *(float4*)(a_st + (long)col * F_ + f0) = a0;
  *(float4*)(a_st + (long)col * F_ + f0 + 4) = a1;
  *(float4*)(b_st + (long)col * F_ + f0) = b0;
  *(float4*)(b_st + (long)col * F_ + f0 + 4) = b1;
  const float bb[8] = {b0.x, b0.y, b0.z, b0.w, b1.x, b1.y, b1.z, b1.w};
  float hv[8];
#pragma unroll
  for (int q = 0; q < 8; ++q) hv[q] = bb[q] + fe_val(f0 + q);
  const int lo = pk4f8(hv[0], hv[1], hv[2], hv[3]);
  const int hi = pk4f8(hv[4], hv[5], hv[6], hv[7]);
  *(int2*)(h + (long)col * F_ + f0) = {lo, hi};
}

// One wave per (b,s) column: shfl-scan cumsum, stats, EMA; fuse next h (fp8)
// or final streams (bf16).
__global__ __launch_bounds__(64) void k_cell(const float* __restrict__ Y3,
                                             float* __restrict__ a_st,
                                             float* __restrict__ b_st,
                                             void* __restrict__ outp,
                                             int last) {
  const int col = blockIdx.x;
  const int s = col & (S_ - 1);
  const int b = col >> 11;
  const int lane = threadIdx.x;
  const int f0 = lane * 8;
  const float* d = Y3 + ((long)(3 * b + 0) * S_ + s) * F_ + f0;
  const float* sc = Y3 + ((long)(3 * b + 1) * S_ + s) * F_ + f0;
  const float* sh = Y3 + ((long)(3 * b + 2) * S_ + s) * F_ + f0;
  float* ap = a_st + (long)col * F_ + f0;
  float* bp = b_st + (long)col * F_ + f0;
  const float inv_div = 1.0f / (float)(s + 1);

  const float4 d0 = *(const float4*)d;
  const float4 d1 = *(const float4*)(d + 4);
  const float4 sc0 = *(const float4*)sc;
  const float4 sc1 = *(const float4*)(sc + 4);
  const float4 sh0 = *(const float4*)sh;
  const float4 sh1 = *(const float4*)(sh + 4);

  float c[8];
  c[0] = d0.x;
  c[1] = c[0] + d0.y;
  c[2] = c[1] + d0.z;
  c[3] = c[2] + d0.w;
  c[4] = c[3] + d1.x;
  c[5] = c[4] + d1.y;
  c[6] = c[5] + d1.z;
  c[7] = c[6] + d1.w;
  const float tot = c[7];
  float scan = tot;
#pragma unroll
  for (int off = 1; off < 64; off <<= 1) {
    float nb = __shfl_up(scan, off);
    if (lane >= off) scan += nb;
  }
  const float base = scan - tot;

  float v[8];
  v[0] = (base + c[0]) * inv_div * sc0.x + sh0.x;
  v[1] = (base + c[1]) * inv_div * sc0.y + sh0.y;
  v[2] = (base + c[2]) * inv_div * sc0.z + sh0.z;
  v[3] = (base + c[3]) * inv_div * sc0.w + sh0.w;
  v[4] = (base + c[4]) * inv_div * sc1.x + sh1.x;
  v[5] = (base + c[5]) * inv_div * sc1.y + sh1.y;
  v[6] = (base + c[6]) * inv_div * sc1.z + sh1.z;
  v[7] = (base + c[7]) * inv_div * sc1.w + sh1.w;

  float sum = 0.f, ssq = 0.f;
#pragma unroll
  for (int q = 0; q < 8; ++q) {
    sum += v[q];
    ssq += v[q] * v[q];
  }
#pragma unroll
  for (int off = 1; off < 64; off <<= 1) {
    sum += __shfl_xor(sum, off);
    ssq += __shfl_xor(ssq, off);
  }
  const float mean = sum * (1.0f / (float)F_);
  const float nsq = fmaxf(ssq - (float)F_ * mean * mean, 0.0f);
  const float denom = sqrtf(nsq) * 0.04419417382415922f + 1e-5f;
  const float isc = 0.7071067811865476f / denom;

  const float4 av0 = *(const float4*)ap;
  const float4 av1 = *(const float4*)(ap + 4);
  const float4 bv0 = *(const float4*)bp;
  const float4 bv1 = *(const float4*)(bp + 4);
  float an[8], bn[8];
  const float ai[8] = {av0.x, av0.y, av0.z, av0.w, av1.x, av1.y, av1.z, av1.w};
  const float bi[8] = {bv0.x, bv0.y, bv0.z, bv0.w, bv1.x, bv1.y, bv1.z, bv1.w};
#pragma unroll
  for (int q = 0; q < 8; ++q) {
    const float cell = (v[q] - mean) * isc;
    an[q] = 0.99f * ai[q] + 0.01f * cell;
    bn[q] = bi[q] + an[q];
  }
  *(float4*)ap = {an[0], an[1], an[2], an[3]};
  *(float4*)(ap + 4) = {an[4], an[5], an[6], an[7]};
  *(float4*)bp = {bn[0], bn[1], bn[2], bn[3]};
  *(float4*)(bp + 4) = {bn[4], bn[5], bn[6], bn[7]};
  if (!last) {
    float hv[8];
#pragma unroll
    for (int q = 0; q < 8; ++q) hv[q] = bn[q] + fe_val(f0 + q);
    const int lo = pk4f8(hv[0], hv[1], hv[2], hv[3]);
    const int hi = pk4f8(hv[4], hv[5], hv[6], hv[7]);
    *(int2*)((u8*)outp + (long)col * F_ + f0) = {lo, hi};
  } else {
    bf8 oa, ob;
#pragma unroll
    for (int q = 0; q < 8; ++q) {
      oa[q] = (__bf16)an[q];
      ob[q] = (__bf16)bn[q];
    }
    *(bf8*)((__bf16*)outp + (long)col * (2 * F_) + f0) = oa;
    *(bf8*)((__bf16*)outp + (long)col * (2 * F_) + F_ + f0) = ob;
  }
}

// Fused logits GEMM (bf16) + bias + softmax + NLL. 32-position tiles,
// grid (64, 2) = 128 blocks for 2x parallelism vs R6.
__global__ __launch_bounds__(256) void k_logits_nll(
    const __bf16* __restrict__ A, const __bf16* __restrict__ Bb,
    const float* __restrict__ outb, const int* __restrict__ tgt,
    float* __restrict__ acc) {
  __shared__ __bf16 As[256 * 32];
  __shared__ __bf16 Bs[32 * 32];
  __shared__ float lsm[32 * 256];
  const int tid = threadIdx.x;
  const int b = blockIdx.y;
  const int n0 = blockIdx.x * 32;
  const __bf16* Bt = Bb + (long)b * (S_ * 2 * F_) + (long)n0 * (2 * F_);
  const int lane = tid & 63;
  const int wave = tid >> 6;
  const int l15 = lane & 15;
  const int quad = lane >> 4;
  const int cr = tid >> 2;
  const int csw = (((tid & 3) ^ ((cr >> 1) & 3)) << 3);
  const int roff = ((quad ^ ((l15 >> 1) & 3)) << 3);
  f4 av[4][2] = {};
  for (int k0 = 0; k0 < 2 * F_; k0 += 32) {
#pragma unroll
    for (int i = 0; i < 4; ++i)
      gload_lds16(A + (long)(i * 64 + cr) * (2 * F_) + (k0 + csw),
                  As + ((i * 256 + (wave << 6)) << 3));
    if (wave < 2)
      gload_lds16(Bt + (long)cr * (2 * F_) + (k0 + csw),
                  Bs + ((wave << 6) << 3));
    __syncthreads();
    bf8 af[4], bfr[2];
#pragma unroll
    for (int mt = 0; mt < 4; ++mt)
      af[mt] = *(const bf8*)(As + (wave * 64 + mt * 16 + l15) * 32 + roff);
#pragma unroll
    for (int nt = 0; nt < 2; ++nt)
      bfr[nt] = *(const bf8*)(Bs + (nt * 16 + l15) * 32 + roff);
#pragma unroll
    for (int mt = 0; mt < 4; ++mt)
#pragma unroll
      for (int nt = 0; nt < 2; ++nt)
        av[mt][nt] = __builtin_amdgcn_mfma_f32_16x16x32_bf16(af[mt], bfr[nt],
                                                             av[mt][nt], 0, 0, 0);
    __syncthreads();
  }
#pragma unroll
  for (int mt = 0; mt < 4; ++mt) {
    const int m = wave * 64 + mt * 16 + quad * 4;
#pragma unroll
    for (int nt = 0; nt < 2; ++nt) {
      const int pp = nt * 16 + l15;
      *(f4*)(lsm + pp * C_ + m) = av[mt][nt];
    }
  }
  __syncthreads();
  const float4 bv = *(const float4*)(outb + lane * 4);
  float wsum = 0.f;
  for (int i = 0; i < 8; ++i) {
    const int pp = wave * 8 + i;
    const f4 lv = *(const f4*)(lsm + pp * C_ + lane * 4);
    const float x0 = lv[0] + bv.x, x1 = lv[1] + bv.y, x2 = lv[2] + bv.z,
                x3 = lv[3] + bv.w;
    float mx = fmaxf(fmaxf(x0, x1), fmaxf(x2, x3));
#pragma unroll
    for (int off = 1; off < 64; off <<= 1) mx = fmaxf(mx, __shfl_xor(mx, off));
    float ss = expf(x0 - mx) + expf(x1 - mx) + expf(x2 - mx) + expf(x3 - mx);
#pragma unroll
    for (int off = 1; off < 64; off <<= 1) ss += __shfl_xor(ss, off);
    if (lane == 0) {
      const int t = tgt[b * S_ + n0 + pp];
      wsum += mx + logf(ss) - (lsm[pp * C_ + t] + outb[t]);
    }
  }
  if (lane == 0) atomicAdd(acc, wsum);
}

__global__ void k_final(const float* __restrict__ acc, float* __restrict__ out) {
  out[0] = acc[0] * (1.0f / 4096.0f);
}

extern "C" void kernel_launch(void* const* d_in, const int* in_sizes, int n_in,
                              void* d_out, int out_size, void* d_ws,
                              size_t ws_size, hipStream_t stream) {
  const int* inp = (const int*)d_in[0];
  const int* tgt = (const int*)d_in[1];
  const float* emb = (const float*)d_in[2];
  const float* w0s = (const float*)d_in[3];
  const float* w1s = (const float*)d_in[4];
  const float* w2s = (const float*)d_in[5];
  const float* out_w = (const float*)d_in[6];
  const float* out_b = (const float*)d_in[7];

  char* ws = (char*)d_ws;
  float* acc = (float*)(ws + 0);
  u8* zp = (u8*)(ws + 256);
  float* a_st = (float*)(ws + 4096);
  float* b_st = (float*)(ws + 8392704L);
  u8* h = (u8*)(ws + 16781312L);            // [b*2048+s][512] fp8
  u8* Y1f8 = (u8*)(ws + 20975616L);         // [b][s][3072] fp8
  u8* Y2f8 = (u8*)(ws + 46141440L);         // [b*3+p][s][1024] fp8
  float* Y3 = (float*)(ws + 71307264L);     // [b*3+p][s][512] f32
  u8* W1f8 = (u8*)(ws + 96473088L);         // [(l*3+p)*I+i][3072] fp8 x64
  __bf16* streams = (__bf16*)(ws + 134221824L);
  u8* W0f8 = (u8*)(ws + 146804736L);        // [l][3072][512] fp8 x64
  u8* W2f8 = (u8*)(ws + 153096192L);        // [l][3*512][1024] fp8 x64
  __bf16* OWc = (__bf16*)(ws + 159387648L);

  hipMemsetAsync(ws, 0, 4096, stream);  // acc + zero page
  k_prep<<<12544, 256, 0, stream>>>(w0s, w2s, out_w, w1s, W0f8, W2f8, OWc, W1f8);
  k_embed<<<4096, 64, 0, stream>>>(inp, emb, a_st, b_st, h);

  for (int l = 0; l < 2; ++l) {
    // conv1: (3I x F) @ h -> Y1 fp8, relu
    gemm_f8<1, true, 2, 128, 512, 512><<<dim3(16, 24, 2), 256, 0, stream>>>(
        W0f8 + (long)l * 1572864L, h, Y1f8, zp, 3072, 1, 0L, 0L, 1048576L,
        6291456L);
    // conv2: causal k=3 (I x 3I) -> Y2 fp8, relu
    gemm_f8<3, true, 2, 128, 1024, 3072><<<dim3(16, 8, 6), 256, 0, stream>>>(
        W1f8 + (long)l * 9437184L, Y1f8, Y2f8, zp, 1024, 3, 3145728L, 1024L,
        6291456L, 2097152L);
    // conv3: (F x I) @ Y2 -> Y3 f32
    gemm_f8<1, false, 0, 64, 1024, 1024><<<dim3(32, 4, 6), 256, 0, stream>>>(
        W2f8 + (long)l * 1572864L, Y2f8, Y3, zp, 512, 3, 524288L, 2097152L,
        6291456L, 1048576L);
    k_cell<<<4096, 64, 0, stream>>>(Y3, a_st, b_st,
                                    (l == 0) ? (void*)h : (void*)streams,
                                    (l == 1) ? 1 : 0);
  }

  k_logits_nll<<<dim3(64, 2), 256, 0, stream>>>(OWc, streams, out_b, tgt, acc);
  k_final<<<1, 1, 0, stream>>>(acc, (float*)d_out);
}

// Round 6
// 360.076 us; speedup vs baseline: 2.9144x; 1.0451x over previous
//
#include <hip/hip_runtime.h>

#define S_ 2048
#define F_ 512
#define I_ 1024
#define C_ 256

typedef float f4 __attribute__((ext_vector_type(4)));
typedef __bf16 bf8 __attribute__((ext_vector_type(8)));
typedef __bf16 bf4 __attribute__((ext_vector_type(4)));
typedef int i4v __attribute__((ext_vector_type(4)));
typedef int i8v __attribute__((ext_vector_type(8)));
typedef unsigned char u8;

__device__ __forceinline__ void gload_lds16(const void* g, void* l) {
  __builtin_amdgcn_global_load_lds(
      (const __attribute__((address_space(1))) void*)g,
      (__attribute__((address_space(3))) void*)l, 16, 0, 0);
}

__device__ __forceinline__ float fe_val(int f) {
  const float PI_F = 3.14159265358979323846f;
  float additive = (f & 1) ? 0.0f : 1.0f;
  float fv = ((float)(f + 1) - additive) * 0.5f;
  fv = fv * (8.0f / (float)F_) - logf((float)C_ / (2.0f * PI_F));
  return expf(fv) + additive * PI_F;
}

// MX-fp8 GEMM, R6-measured LDS layout: 128-B rows, 16-B chunk slot s of row r
// holds chunk s ^ (r&7). C[n][m] = (1/64)*sum_k A[m][k]*B'[k][n].
// KW=3 causal: k = t*KD + j, B row (n + t - 2), zero page if < 0.
// OUT: 0 = f32, 2 = fp8-e4m3. Output n-major (ldc = M).
//
// R12: R10's B-dbuf schedule + register diet. Key discovery (R10/R11
// counters): gfx950 unified VGPR+AGPR file -> per-wave alloc = VGPR_Count +
// 64 (acc AGPRs); 3 waves/SIMD needs VGPR_Count <= ~106. R10's schedule was
// correct but VGPR=116 (180 total) -> 2 blocks/CU cliff. Diet: one invariant
// per-thread base pointer per matrix + wave-uniform per-step offsets; no
// per-g/per-step pointer recomputation. launch_bounds(256,3) pins 3 waves/EU.
// LDS = A 16KB + B 2x16KB = 48KB (3x48=144 <= 160 OK). Natural k-order (R8).
// Per k-step: stageB(next) issues before compute -> post-compute barrier
// drains it under MFMA cover; only the 16KB A-stage is exposed (half of R6).
template <int KW, bool RELU, int OUT, int NTILE, int KD, int LDB>
__global__ __launch_bounds__(256, 3) void gemm_f8(
    const u8* __restrict__ Ab, const u8* __restrict__ Bb, void* __restrict__ Cb,
    const u8* __restrict__ zpage, int M, int PZ, long sAp, long sBp, long sBb,
    long sCz) {
  constexpr int NF = NTILE / 32;  // n-frags per wave
  constexpr int NIT = KD / 128;   // 128-byte k-steps per segment
  constexpr int AK = KW * KD;     // A row stride
  constexpr int BP = NTILE / 32;  // B staging passes (32 rows each)
  constexpr int NSTEP = KW * NIT;
  constexpr int LOG_NIT = (NIT == 4) ? 2 : 3;
  static_assert(NIT == (1 << LOG_NIT), "NIT pow2");
  static_assert(NSTEP % 2 == 0, "even k-step count required");
  __shared__ u8 Asm[128 * 128];
  __shared__ u8 Bsm[2][NTILE * 128];
  const int tid = threadIdx.x;
  const int z = blockIdx.z;
  const int p = z % PZ;
  const int bb = z / PZ;
  const u8* A = Ab + (long)p * sAp;
  const u8* B = Bb + (long)bb * sBb + (long)p * sBp;
  const int m0 = blockIdx.y * 128;
  const int n0 = blockIdx.x * NTILE;
  const int lane = tid & 63;
  const int wave = tid >> 6;
  const int wr = wave >> 1;
  const int wc = wave & 1;
  const int l15 = lane & 15;
  const int quad = lane >> 4;
  const int cr = tid >> 3;                        // staged row within pass
  const int csw = (((tid & 7) ^ (cr & 7)) << 4);  // fetched chunk
  const int off0 = (((2 * quad) ^ (l15 & 7)) << 4);
  const int off1 = (((2 * quad + 1) ^ (l15 & 7)) << 4);
  f4 acc[4][NF] = {};

  // Loop-invariant per-thread bases; everything per-step is a uniform add.
  const u8* pA0 = A + (long)(m0 + cr) * AK + csw;
  const int rb0 = n0 + cr + ((KW == 3) ? -2 : 0);  // B row base (g=0)
  const u8* pB0 = B + (long)rb0 * LDB + csw;
  const u8* zpc = zpage + csw;

  // uniform offsets for k-step ks: t = ks>>LOG_NIT, kb = ks&(NIT-1)
  auto stageA = [&](int ks) {
    const int uoff = ((ks >> LOG_NIT) * KD) + ((ks & (NIT - 1)) << 7);
#pragma unroll
    for (int g = 0; g < 4; ++g)
      gload_lds16(pA0 + (long)(g * 32) * AK + uoff,
                  Asm + g * 4096 + wave * 1024);
  };

  auto stageB = [&](int ks, int buf) {
    const int t = ks >> LOG_NIT;
    const int uoff = t * LDB + ((ks & (NIT - 1)) << 7);
#pragma unroll
    for (int g = 0; g < BP; ++g) {
      const u8* src = pB0 + (long)(g * 32) * LDB + uoff;
      if (KW == 3 && (rb0 + g * 32 + t) < 0) src = zpc;
      gload_lds16(src, &Bsm[buf][g * 4096 + wave * 1024]);
    }
  };

  auto compute = [&](int buf) {
    i8v af[4], bfr[NF];
#pragma unroll
    for (int mt = 0; mt < 4; ++mt) {
      const u8* rp = Asm + (wr * 64 + mt * 16 + l15) * 128;
      const i4v lo = *(const i4v*)(rp + off0);
      const i4v hi = *(const i4v*)(rp + off1);
      af[mt][0] = lo[0]; af[mt][1] = lo[1]; af[mt][2] = lo[2]; af[mt][3] = lo[3];
      af[mt][4] = hi[0]; af[mt][5] = hi[1]; af[mt][6] = hi[2]; af[mt][7] = hi[3];
    }
#pragma unroll
    for (int nt = 0; nt < NF; ++nt) {
      const u8* rp = &Bsm[buf][(wc * (NTILE / 2) + nt * 16 + l15) * 128];
      const i4v lo = *(const i4v*)(rp + off0);
      const i4v hi = *(const i4v*)(rp + off1);
      bfr[nt][0] = lo[0]; bfr[nt][1] = lo[1]; bfr[nt][2] = lo[2]; bfr[nt][3] = lo[3];
      bfr[nt][4] = hi[0]; bfr[nt][5] = hi[1]; bfr[nt][6] = hi[2]; bfr[nt][7] = hi[3];
    }
#pragma unroll
    for (int mt = 0; mt < 4; ++mt)
#pragma unroll
      for (int nt = 0; nt < NF; ++nt)
        acc[mt][nt] = __builtin_amdgcn_mfma_scale_f32_16x16x128_f8f6f4(
            af[mt], bfr[nt], acc[mt][nt], 0, 0, 0, 0x7F7F7F7F, 0, 0x7F7F7F7F);
  };

  stageA(0);
  stageB(0, 0);
  __syncthreads();
#pragma unroll 1
  for (int ks = 0; ks < NSTEP; ks += 2) {
    stageB(ks + 1, 1);   // prefetch next B; in flight under compute
    compute(0);
    __syncthreads();     // drains B(ks+1); Asm reads done
    stageA(ks + 1);      // only A (16KB) exposed here
    __syncthreads();
    if (ks + 2 < NSTEP) stageB(ks + 2, 0);
    compute(1);
    __syncthreads();
    if (ks + 2 < NSTEP) {
      stageA(ks + 2);
      __syncthreads();
    }
  }

#pragma unroll
  for (int mt = 0; mt < 4; ++mt) {
    const int m = m0 + wr * 64 + mt * 16 + quad * 4;
#pragma unroll
    for (int nt = 0; nt < NF; ++nt) {
      const int n = n0 + wc * (NTILE / 2) + nt * 16 + l15;
      f4 v = acc[mt][nt];
#pragma unroll
      for (int q = 0; q < 4; ++q) {
        v[q] *= 0.015625f;  // undo weight x64
        if (RELU) v[q] = fmaxf(v[q], 0.0f);
      }
      if (OUT == 2) {
        int r = __builtin_amdgcn_cvt_pk_fp8_f32(v[0], v[1], 0, false);
        r = __builtin_amdgcn_cvt_pk_fp8_f32(v[2], v[3], r, true);
        *(int*)((u8*)Cb + (long)z * sCz + (long)n * M + m) = r;
      } else {
        *(f4*)((float*)Cb + (long)z * sCz + (long)n * M + m) = v;
      }
    }
  }
}

__device__ __forceinline__ void cvt4(const float* __restrict__ s,
                                     __bf16* __restrict__ d, long T) {
  const long i = T * 4;
  const float4 v = *(const float4*)(s + i);
  bf4 o;
  o[0] = (__bf16)v.x;
  o[1] = (__bf16)v.y;
  o[2] = (__bf16)v.z;
  o[3] = (__bf16)v.w;
  *(bf4*)(d + i) = o;
}

__device__ __forceinline__ void cvt4f8(const float* __restrict__ s,
                                       u8* __restrict__ d, long T) {
  const long i = T * 4;
  const float4 v = *(const float4*)(s + i);
  int r = __builtin_amdgcn_cvt_pk_fp8_f32(v.x * 64.0f, v.y * 64.0f, 0, false);
  r = __builtin_amdgcn_cvt_pk_fp8_f32(v.z * 64.0f, v.w * 64.0f, r, true);
  *(int*)(d + i) = r;
}

__device__ __forceinline__ int pk4f8(float a, float b, float c, float d) {
  int r = __builtin_amdgcn_cvt_pk_fp8_f32(a, b, 0, false);
  return __builtin_amdgcn_cvt_pk_fp8_f32(c, d, r, true);
}

// One dispatch: w0s/w2s -> fp8 x64, out_w -> bf16, w1s reorder -> fp8 x64.
// w1 path vectorized: thread handles 4 j's (3 float4 reads, 3 int stores).
__global__ void k_prep(const float* __restrict__ w0, const float* __restrict__ w2,
                       const float* __restrict__ ow, const float* __restrict__ w1,
                       u8* __restrict__ W0f8, u8* __restrict__ W2f8,
                       __bf16* __restrict__ OWc, u8* __restrict__ W1f8) {
  long T = (long)blockIdx.x * 256 + threadIdx.x;
  if (T < 786432L) {
    cvt4f8(w0, W0f8, T);
    return;
  }
  T -= 786432L;
  if (T < 786432L) {
    cvt4f8(w2, W2f8, T);
    return;
  }
  T -= 786432L;
  if (T < 65536L) {
    cvt4(ow, OWc, T);
    return;
  }
  T -= 65536L;
  // w1s (L,3,I,I,K=3) -> W1f8[(l*3+p)*I+i][t*1024 + j], value x64
  const long j4 = T & 255;   // group of 4 j's
  const long r3 = T >> 8;
  const float* src = w1 + r3 * 3072 + j4 * 12;
  const float4 v0 = *(const float4*)src;       // j0t0 j0t1 j0t2 j1t0
  const float4 v1 = *(const float4*)(src + 4); // j1t1 j1t2 j2t0 j2t1
  const float4 v2 = *(const float4*)(src + 8); // j2t2 j3t0 j3t1 j3t2
  u8* dst = W1f8 + r3 * 3072 + j4 * 4;
  *(int*)(dst) = pk4f8(v0.x * 64.f, v0.w * 64.f, v1.z * 64.f, v2.y * 64.f);
  *(int*)(dst + 1024) = pk4f8(v0.y * 64.f, v1.x * 64.f, v1.w * 64.f, v2.z * 64.f);
  *(int*)(dst + 2048) = pk4f8(v0.z * 64.f, v1.y * 64.f, v2.x * 64.f, v2.w * 64.f);
}

// One wave per (b,s): gather embedding -> a/b state (f32) + layer-0 h (fp8).
__global__ __launch_bounds__(64) void k_embed(const int* __restrict__ inp,
                                              const float* __restrict__ emb,
                                              float* __restrict__ a_st,
                                              float* __restrict__ b_st,
                                              u8* __restrict__ h) {
  const int col = blockIdx.x;
  const int lane = threadIdx.x;
  const int f0 = lane * 8;
  const float* e = emb + (long)inp[col] * (2 * F_);
  const float4 a0 = *(const float4*)(e + f0);
  const float4 a1 = *(const float4*)(e + f0 + 4);
  const float4 b0 = *(const float4*)(e + F_ + f0);
  const float4 b1 = *(const float4*)(e + F_ + f0 + 4);
  *(float4*)(a_st + (long)col * F_ + f0) = a0;
  *(float4*)(a_st + (long)col * F_ + f0 + 4) = a1;
  *(float4*)(b_st + (long)col * F_ + f0) = b0;
  *(float4*)(b_st + (long)col * F_ + f0 + 4) = b1;
  const float bb[8] = {b0.x, b0.y, b0.z, b0.w, b1.x, b1.y, b1.z, b1.w};
  float hv[8];
#pragma unroll
  for (int q = 0; q < 8; ++q) hv[q] = bb[q] + fe_val(f0 + q);
  const int lo = pk4f8(hv[0], hv[1], hv[2], hv[3]);
  const int hi = pk4f8(hv[4], hv[5], hv[6], hv[7]);
  *(int2*)(h + (long)col * F_ + f0) = {lo, hi};
}

// One wave per (b,s) column: shfl-scan cumsum, stats, EMA; fuse next h (fp8)
// or final streams (bf16).
__global__ __launch_bounds__(64) void k_cell(const float* __restrict__ Y3,
                                             float* __restrict__ a_st,
                                             float* __restrict__ b_st,
                                             void* __restrict__ outp,
                                             int last) {
  const int col = blockIdx.x;
  const int s = col & (S_ - 1);
  const int b = col >> 11;
  const int lane = threadIdx.x;
  const int f0 = lane * 8;
  const float* d = Y3 + ((long)(3 * b + 0) * S_ + s) * F_ + f0;
  const float* sc = Y3 + ((long)(3 * b + 1) * S_ + s) * F_ + f0;
  const float* sh = Y3 + ((long)(3 * b + 2) * S_ + s) * F_ + f0;
  float* ap = a_st + (long)col * F_ + f0;
  float* bp = b_st + (long)col * F_ + f0;
  const float inv_div = 1.0f / (float)(s + 1);

  const float4 d0 = *(const float4*)d;
  const float4 d1 = *(const float4*)(d + 4);
  const float4 sc0 = *(const float4*)sc;
  const float4 sc1 = *(const float4*)(sc + 4);
  const float4 sh0 = *(const float4*)sh;
  const float4 sh1 = *(const float4*)(sh + 4);

  float c[8];
  c[0] = d0.x;
  c[1] = c[0] + d0.y;
  c[2] = c[1] + d0.z;
  c[3] = c[2] + d0.w;
  c[4] = c[3] + d1.x;
  c[5] = c[4] + d1.y;
  c[6] = c[5] + d1.z;
  c[7] = c[6] + d1.w;
  const float tot = c[7];
  float scan = tot;
#pragma unroll
  for (int off = 1; off < 64; off <<= 1) {
    float nb = __shfl_up(scan, off);
    if (lane >= off) scan += nb;
  }
  const float base = scan - tot;

  float v[8];
  v[0] = (base + c[0]) * inv_div * sc0.x + sh0.x;
  v[1] = (base + c[1]) * inv_div * sc0.y + sh0.y;
  v[2] = (base + c[2]) * inv_div * sc0.z + sh0.z;
  v[3] = (base + c[3]) * inv_div * sc0.w + sh0.w;
  v[4] = (base + c[4]) * inv_div * sc1.x + sh1.x;
  v[5] = (base + c[5]) * inv_div * sc1.y + sh1.y;
  v[6] = (base + c[6]) * inv_div * sc1.z + sh1.z;
  v[7] = (base + c[7]) * inv_div * sc1.w + sh1.w;

  float sum = 0.f, ssq = 0.f;
#pragma unroll
  for (int q = 0; q < 8; ++q) {
    sum += v[q];
    ssq += v[q] * v[q];
  }
#pragma unroll
  for (int off = 1; off < 64; off <<= 1) {
    sum += __shfl_xor(sum, off);
    ssq += __shfl_xor(ssq, off);
  }
  const float mean = sum * (1.0f / (float)F_);
  const float nsq = fmaxf(ssq - (float)F_ * mean * mean, 0.0f);
  const float denom = sqrtf(nsq) * 0.04419417382415922f + 1e-5f;
  const float isc = 0.7071067811865476f / denom;

  const float4 av0 = *(const float4*)ap;
  const float4 av1 = *(const float4*)(ap + 4);
  const float4 bv0 = *(const float4*)bp;
  const float4 bv1 = *(const float4*)(bp + 4);
  float an[8], bn[8];
  const float ai[8] = {av0.x, av0.y, av0.z, av0.w, av1.x, av1.y, av1.z, av1.w};
  const float bi[8] = {bv0.x, bv0.y, bv0.z, bv0.w, bv1.x, bv1.y, bv1.z, bv1.w};
#pragma unroll
  for (int q = 0; q < 8; ++q) {
    const float cell = (v[q] - mean) * isc;
    an[q] = 0.99f * ai[q] + 0.01f * cell;
    bn[q] = bi[q] + an[q];
  }
  *(float4*)ap = {an[0], an[1], an[2], an[3]};
  *(float4*)(ap + 4) = {an[4], an[5], an[6], an[7]};
  *(float4*)bp = {bn[0], bn[1], bn[2], bn[3]};
  *(float4*)(bp + 4) = {bn[4], bn[5], bn[6], bn[7]};
  if (!last) {
    float hv[8];
#pragma unroll
    for (int q = 0; q < 8; ++q) hv[q] = bn[q] + fe_val(f0 + q);
    const int lo = pk4f8(hv[0], hv[1], hv[2], hv[3]);
    const int hi = pk4f8(hv[4], hv[5], hv[6], hv[7]);
    *(int2*)((u8*)outp + (long)col * F_ + f0) = {lo, hi};
  } else {
    bf8 oa, ob;
#pragma unroll
    for (int q = 0; q < 8; ++q) {
      oa[q] = (__bf16)an[q];
      ob[q] = (__bf16)bn[q];
    }
    *(bf8*)((__bf16*)outp + (long)col * (2 * F_) + f0) = oa;
    *(bf8*)((__bf16*)outp + (long)col * (2 * F_) + F_ + f0) = ob;
  }
}

// Fused logits GEMM (bf16) + bias + softmax + NLL. 32-position tiles,
// grid (64, 2) = 128 blocks for 2x parallelism vs R6.
__global__ __launch_bounds__(256) void k_logits_nll(
    const __bf16* __restrict__ A, const __bf16* __restrict__ Bb,
    const float* __restrict__ outb, const int* __restrict__ tgt,
    float* __restrict__ acc) {
  __shared__ __bf16 As[256 * 32];
  __shared__ __bf16 Bs[32 * 32];
  __shared__ float lsm[32 * 256];
  const int tid = threadIdx.x;
  const int b = blockIdx.y;
  const int n0 = blockIdx.x * 32;
  const __bf16* Bt = Bb + (long)b * (S_ * 2 * F_) + (long)n0 * (2 * F_);
  const int lane = tid & 63;
  const int wave = tid >> 6;
  const int l15 = lane & 15;
  const int quad = lane >> 4;
  const int cr = tid >> 2;
  const int csw = (((tid & 3) ^ ((cr >> 1) & 3)) << 3);
  const int roff = ((quad ^ ((l15 >> 1) & 3)) << 3);
  f4 av[4][2] = {};
  for (int k0 = 0; k0 < 2 * F_; k0 += 32) {
#pragma unroll
    for (int i = 0; i < 4; ++i)
      gload_lds16(A + (long)(i * 64 + cr) * (2 * F_) + (k0 + csw),
                  As + ((i * 256 + (wave << 6)) << 3));
    if (wave < 2)
      gload_lds16(Bt + (long)cr * (2 * F_) + (k0 + csw),
                  Bs + ((wave << 6) << 3));
    __syncthreads();
    bf8 af[4], bfr[2];
#pragma unroll
    for (int mt = 0; mt < 4; ++mt)
      af[mt] = *(const bf8*)(As + (wave * 64 + mt * 16 + l15) * 32 + roff);
#pragma unroll
    for (int nt = 0; nt < 2; ++nt)
      bfr[nt] = *(const bf8*)(Bs + (nt * 16 + l15) * 32 + roff);
#pragma unroll
    for (int mt = 0; mt < 4; ++mt)
#pragma unroll
      for (int nt = 0; nt < 2; ++nt)
        av[mt][nt] = __builtin_amdgcn_mfma_f32_16x16x32_bf16(af[mt], bfr[nt],
                                                             av[mt][nt], 0, 0, 0);
    __syncthreads();
  }
#pragma unroll
  for (int mt = 0; mt < 4; ++mt) {
    const int m = wave * 64 + mt * 16 + quad * 4;
#pragma unroll
    for (int nt = 0; nt < 2; ++nt) {
      const int pp = nt * 16 + l15;
      *(f4*)(lsm + pp * C_ + m) = av[mt][nt];
    }
  }
  __syncthreads();
  const float4 bv = *(const float4*)(outb + lane * 4);
  float wsum = 0.f;
  for (int i = 0; i < 8; ++i) {
    const int pp = wave * 8 + i;
    const f4 lv = *(const f4*)(lsm + pp * C_ + lane * 4);
    const float x0 = lv[0] + bv.x, x1 = lv[1] + bv.y, x2 = lv[2] + bv.z,
                x3 = lv[3] + bv.w;
    float mx = fmaxf(fmaxf(x0, x1), fmaxf(x2, x3));
#pragma unroll
    for (int off = 1; off < 64; off <<= 1) mx = fmaxf(mx, __shfl_xor(mx, off));
    float ss = expf(x0 - mx) + expf(x1 - mx) + expf(x2 - mx) + expf(x3 - mx);
#pragma unroll
    for (int off = 1; off < 64; off <<= 1) ss += __shfl_xor(ss, off);
    if (lane == 0) {
      const int t = tgt[b * S_ + n0 + pp];
      wsum += mx + logf(ss) - (lsm[pp * C_ + t] + outb[t]);
    }
  }
  if (lane == 0) atomicAdd(acc, wsum);
}

__global__ void k_final(const float* __restrict__ acc, float* __restrict__ out) {
  out[0] = acc[0] * (1.0f / 4096.0f);
}

extern "C" void kernel_launch(void* const* d_in, const int* in_sizes, int n_in,
                              void* d_out, int out_size, void* d_ws,
                              size_t ws_size, hipStream_t stream) {
  const int* inp = (const int*)d_in[0];
  const int* tgt = (const int*)d_in[1];
  const float* emb = (const float*)d_in[2];
  const float* w0s = (const float*)d_in[3];
  const float* w1s = (const float*)d_in[4];
  const float* w2s = (const float*)d_in[5];
  const float* out_w = (const float*)d_in[6];
  const float* out_b = (const float*)d_in[7];

  char* ws = (char*)d_ws;
  float* acc = (float*)(ws + 0);
  u8* zp = (u8*)(ws + 256);
  float* a_st = (float*)(ws + 4096);
  float* b_st = (float*)(ws + 8392704L);
  u8* h = (u8*)(ws + 16781312L);            // [b*2048+s][512] fp8
  u8* Y1f8 = (u8*)(ws + 20975616L);         // [b][s][3072] fp8
  u8* Y2f8 = (u8*)(ws + 46141440L);         // [b*3+p][s][1024] fp8
  float* Y3 = (float*)(ws + 71307264L);     // [b*3+p][s][512] f32
  u8* W1f8 = (u8*)(ws + 96473088L);         // [(l*3+p)*I+i][3072] fp8 x64
  __bf16* streams = (__bf16*)(ws + 134221824L);
  u8* W0f8 = (u8*)(ws + 146804736L);        // [l][3072][512] fp8 x64
  u8* W2f8 = (u8*)(ws + 153096192L);        // [l][3*512][1024] fp8 x64
  __bf16* OWc = (__bf16*)(ws + 159387648L);

  hipMemsetAsync(ws, 0, 4096, stream);  // acc + zero page
  k_prep<<<12544, 256, 0, stream>>>(w0s, w2s, out_w, w1s, W0f8, W2f8, OWc, W1f8);
  k_embed<<<4096, 64, 0, stream>>>(inp, emb, a_st, b_st, h);

  for (int l = 0; l < 2; ++l) {
    // conv1: (3I x F) @ h -> Y1 fp8, relu
    gemm_f8<1, true, 2, 128, 512, 512><<<dim3(16, 24, 2), 256, 0, stream>>>(
        W0f8 + (long)l * 1572864L, h, Y1f8, zp, 3072, 1, 0L, 0L, 1048576L,
        6291456L);
    // conv2: causal k=3 (I x 3I) -> Y2 fp8, relu
    gemm_f8<3, true, 2, 128, 1024, 3072><<<dim3(16, 8, 6), 256, 0, stream>>>(
        W1f8 + (long)l * 9437184L, Y1f8, Y2f8, zp, 1024, 3, 3145728L, 1024L,
        6291456L, 2097152L);
    // conv3: (F x I) @ Y2 -> Y3 f32
    gemm_f8<1, false, 0, 64, 1024, 1024><<<dim3(32, 4, 6), 256, 0, stream>>>(
        W2f8 + (long)l * 1572864L, Y2f8, Y3, zp, 512, 3, 524288L, 2097152L,
        6291456L, 1048576L);
    k_cell<<<4096, 64, 0, stream>>>(Y3, a_st, b_st,
                                    (l == 0) ? (void*)h : (void*)streams,
                                    (l == 1) ? 1 : 0);
  }

  k_logits_nll<<<dim3(64, 2), 256, 0, stream>>>(OWc, streams, out_b, tgt, acc);
  k_final<<<1, 1, 0, stream>>>(acc, (float*)d_out);
}

// Round 7
// 357.459 us; speedup vs baseline: 2.9357x; 1.0073x over previous
//
#include <hip/hip_runtime.h>

#define S_ 2048
#define F_ 512
#define I_ 1024
#define C_ 256

typedef float f4 __attribute__((ext_vector_type(4)));
typedef __bf16 bf8 __attribute__((ext_vector_type(8)));
typedef __bf16 bf4 __attribute__((ext_vector_type(4)));
typedef int i4v __attribute__((ext_vector_type(4)));
typedef int i8v __attribute__((ext_vector_type(8)));
typedef unsigned char u8;

__device__ __forceinline__ void gload_lds16(const void* g, void* l) {
  __builtin_amdgcn_global_load_lds(
      (const __attribute__((address_space(1))) void*)g,
      (__attribute__((address_space(3))) void*)l, 16, 0, 0);
}

__device__ __forceinline__ float fe_val(int f) {
  const float PI_F = 3.14159265358979323846f;
  float additive = (f & 1) ? 0.0f : 1.0f;
  float fv = ((float)(f + 1) - additive) * 0.5f;
  fv = fv * (8.0f / (float)F_) - logf((float)C_ / (2.0f * PI_F));
  return expf(fv) + additive * PI_F;
}

// MX-fp8 GEMM, R6-measured LDS layout: 128-B rows, 16-B chunk slot s of row r
// holds chunk s ^ (r&7). C[n][m] = (1/64)*sum_k A[m][k]*B'[k][n].
// KW=3 causal: k = t*KD + j, B row (n + t - 2), zero page if < 0.
// OUT: 0 = f32, 2 = fp8-e4m3. Output n-major (ldc = M).
//
// R13: GEMM frozen at R12 (register-diet B-dbuf; measured == R6 within noise,
// VGPR 84, 3 blocks/CU). conv2 runs 1507 TF = 93% of the m148 structure
// ceiling — further GEMM gains need the 8-phase rewrite, deferred. This
// round attacks dispatch count + small-kernel shapes instead.
template <int KW, bool RELU, int OUT, int NTILE, int KD, int LDB>
__global__ __launch_bounds__(256, 3) void gemm_f8(
    const u8* __restrict__ Ab, const u8* __restrict__ Bb, void* __restrict__ Cb,
    const u8* __restrict__ zpage, int M, int PZ, long sAp, long sBp, long sBb,
    long sCz) {
  constexpr int NF = NTILE / 32;  // n-frags per wave
  constexpr int NIT = KD / 128;   // 128-byte k-steps per segment
  constexpr int AK = KW * KD;     // A row stride
  constexpr int BP = NTILE / 32;  // B staging passes (32 rows each)
  constexpr int NSTEP = KW * NIT;
  constexpr int LOG_NIT = (NIT == 4) ? 2 : 3;
  static_assert(NIT == (1 << LOG_NIT), "NIT pow2");
  static_assert(NSTEP % 2 == 0, "even k-step count required");
  __shared__ u8 Asm[128 * 128];
  __shared__ u8 Bsm[2][NTILE * 128];
  const int tid = threadIdx.x;
  const int z = blockIdx.z;
  const int p = z % PZ;
  const int bb = z / PZ;
  const u8* A = Ab + (long)p * sAp;
  const u8* B = Bb + (long)bb * sBb + (long)p * sBp;
  const int m0 = blockIdx.y * 128;
  const int n0 = blockIdx.x * NTILE;
  const int lane = tid & 63;
  const int wave = tid >> 6;
  const int wr = wave >> 1;
  const int wc = wave & 1;
  const int l15 = lane & 15;
  const int quad = lane >> 4;
  const int cr = tid >> 3;                        // staged row within pass
  const int csw = (((tid & 7) ^ (cr & 7)) << 4);  // fetched chunk
  const int off0 = (((2 * quad) ^ (l15 & 7)) << 4);
  const int off1 = (((2 * quad + 1) ^ (l15 & 7)) << 4);
  f4 acc[4][NF] = {};

  // Loop-invariant per-thread bases; everything per-step is a uniform add.
  const u8* pA0 = A + (long)(m0 + cr) * AK + csw;
  const int rb0 = n0 + cr + ((KW == 3) ? -2 : 0);  // B row base (g=0)
  const u8* pB0 = B + (long)rb0 * LDB + csw;
  const u8* zpc = zpage + csw;

  // uniform offsets for k-step ks: t = ks>>LOG_NIT, kb = ks&(NIT-1)
  auto stageA = [&](int ks) {
    const int uoff = ((ks >> LOG_NIT) * KD) + ((ks & (NIT - 1)) << 7);
#pragma unroll
    for (int g = 0; g < 4; ++g)
      gload_lds16(pA0 + (long)(g * 32) * AK + uoff,
                  Asm + g * 4096 + wave * 1024);
  };

  auto stageB = [&](int ks, int buf) {
    const int t = ks >> LOG_NIT;
    const int uoff = t * LDB + ((ks & (NIT - 1)) << 7);
#pragma unroll
    for (int g = 0; g < BP; ++g) {
      const u8* src = pB0 + (long)(g * 32) * LDB + uoff;
      if (KW == 3 && (rb0 + g * 32 + t) < 0) src = zpc;
      gload_lds16(src, &Bsm[buf][g * 4096 + wave * 1024]);
    }
  };

  auto compute = [&](int buf) {
    i8v af[4], bfr[NF];
#pragma unroll
    for (int mt = 0; mt < 4; ++mt) {
      const u8* rp = Asm + (wr * 64 + mt * 16 + l15) * 128;
      const i4v lo = *(const i4v*)(rp + off0);
      const i4v hi = *(const i4v*)(rp + off1);
      af[mt][0] = lo[0]; af[mt][1] = lo[1]; af[mt][2] = lo[2]; af[mt][3] = lo[3];
      af[mt][4] = hi[0]; af[mt][5] = hi[1]; af[mt][6] = hi[2]; af[mt][7] = hi[3];
    }
#pragma unroll
    for (int nt = 0; nt < NF; ++nt) {
      const u8* rp = &Bsm[buf][(wc * (NTILE / 2) + nt * 16 + l15) * 128];
      const i4v lo = *(const i4v*)(rp + off0);
      const i4v hi = *(const i4v*)(rp + off1);
      bfr[nt][0] = lo[0]; bfr[nt][1] = lo[1]; bfr[nt][2] = lo[2]; bfr[nt][3] = lo[3];
      bfr[nt][4] = hi[0]; bfr[nt][5] = hi[1]; bfr[nt][6] = hi[2]; bfr[nt][7] = hi[3];
    }
#pragma unroll
    for (int mt = 0; mt < 4; ++mt)
#pragma unroll
      for (int nt = 0; nt < NF; ++nt)
        acc[mt][nt] = __builtin_amdgcn_mfma_scale_f32_16x16x128_f8f6f4(
            af[mt], bfr[nt], acc[mt][nt], 0, 0, 0, 0x7F7F7F7F, 0, 0x7F7F7F7F);
  };

  stageA(0);
  stageB(0, 0);
  __syncthreads();
#pragma unroll 1
  for (int ks = 0; ks < NSTEP; ks += 2) {
    stageB(ks + 1, 1);   // prefetch next B; in flight under compute
    compute(0);
    __syncthreads();     // drains B(ks+1); Asm reads done
    stageA(ks + 1);      // only A (16KB) exposed here
    __syncthreads();
    if (ks + 2 < NSTEP) stageB(ks + 2, 0);
    compute(1);
    __syncthreads();
    if (ks + 2 < NSTEP) {
      stageA(ks + 2);
      __syncthreads();
    }
  }

#pragma unroll
  for (int mt = 0; mt < 4; ++mt) {
    const int m = m0 + wr * 64 + mt * 16 + quad * 4;
#pragma unroll
    for (int nt = 0; nt < NF; ++nt) {
      const int n = n0 + wc * (NTILE / 2) + nt * 16 + l15;
      f4 v = acc[mt][nt];
#pragma unroll
      for (int q = 0; q < 4; ++q) {
        v[q] *= 0.015625f;  // undo weight x64
        if (RELU) v[q] = fmaxf(v[q], 0.0f);
      }
      if (OUT == 2) {
        int r = __builtin_amdgcn_cvt_pk_fp8_f32(v[0], v[1], 0, false);
        r = __builtin_amdgcn_cvt_pk_fp8_f32(v[2], v[3], r, true);
        *(int*)((u8*)Cb + (long)z * sCz + (long)n * M + m) = r;
      } else {
        *(f4*)((float*)Cb + (long)z * sCz + (long)n * M + m) = v;
      }
    }
  }
}

__device__ __forceinline__ void cvt4(const float* __restrict__ s,
                                     __bf16* __restrict__ d, long T) {
  const long i = T * 4;
  const float4 v = *(const float4*)(s + i);
  bf4 o;
  o[0] = (__bf16)v.x;
  o[1] = (__bf16)v.y;
  o[2] = (__bf16)v.z;
  o[3] = (__bf16)v.w;
  *(bf4*)(d + i) = o;
}

__device__ __forceinline__ void cvt4f8(const float* __restrict__ s,
                                       u8* __restrict__ d, long T) {
  const long i = T * 4;
  const float4 v = *(const float4*)(s + i);
  int r = __builtin_amdgcn_cvt_pk_fp8_f32(v.x * 64.0f, v.y * 64.0f, 0, false);
  r = __builtin_amdgcn_cvt_pk_fp8_f32(v.z * 64.0f, v.w * 64.0f, r, true);
  *(int*)(d + i) = r;
}

__device__ __forceinline__ int pk4f8(float a, float b, float c, float d) {
  int r = __builtin_amdgcn_cvt_pk_fp8_f32(a, b, 0, false);
  return __builtin_amdgcn_cvt_pk_fp8_f32(c, d, r, true);
}

// R13 merged prologue kernel — one dispatch replaces {hipMemsetAsync, k_prep,
// k_embed}:
//   blocks [0, 12544): weight conversion (w0s/w2s -> fp8 x64, out_w -> bf16,
//                      w1s reorder -> fp8 x64), identical math to R6's k_prep.
//   blocks [12544, 13568): embedding gather (4 cols per 256-thr block).
//   block 13568: zero ws[0..4096) (acc @+0, done-counter @+16, zpage @+256).
__global__ void k_prep(const float* __restrict__ w0, const float* __restrict__ w2,
                       const float* __restrict__ ow, const float* __restrict__ w1,
                       u8* __restrict__ W0f8, u8* __restrict__ W2f8,
                       __bf16* __restrict__ OWc, u8* __restrict__ W1f8,
                       const int* __restrict__ inp, const float* __restrict__ emb,
                       float* __restrict__ a_st, float* __restrict__ b_st,
                       u8* __restrict__ h, int* __restrict__ wsz) {
  const int bx = blockIdx.x;
  const int tid = threadIdx.x;
  if (bx >= 13568) {  // zero block
    i4v zv = {0, 0, 0, 0};
    *(i4v*)((u8*)wsz + tid * 16) = zv;
    return;
  }
  if (bx >= 12544) {  // embed: col = (bx-12544)*4 + wave
    const int col = ((bx - 12544) << 2) + (tid >> 6);
    const int lane = tid & 63;
    const int f0 = lane * 8;
    const float* e = emb + (long)inp[col] * (2 * F_);
    const float4 a0 = *(const float4*)(e + f0);
    const float4 a1 = *(const float4*)(e + f0 + 4);
    const float4 b0 = *(const float4*)(e + F_ + f0);
    const float4 b1 = *(const float4*)(e + F_ + f0 + 4);
    *(float4*)(a_st + (long)col * F_ + f0) = a0;
    *(float4*)(a_st + (long)col * F_ + f0 + 4) = a1;
    *(float4*)(b_st + (long)col * F_ + f0) = b0;
    *(float4*)(b_st + (long)col * F_ + f0 + 4) = b1;
    const float bb[8] = {b0.x, b0.y, b0.z, b0.w, b1.x, b1.y, b1.z, b1.w};
    float hv[8];
#pragma unroll
    for (int q = 0; q < 8; ++q) hv[q] = bb[q] + fe_val(f0 + q);
    const int lo = pk4f8(hv[0], hv[1], hv[2], hv[3]);
    const int hi = pk4f8(hv[4], hv[5], hv[6], hv[7]);
    *(int2*)(h + (long)col * F_ + f0) = {lo, hi};
    return;
  }
  long T = (long)bx * 256 + tid;
  if (T < 786432L) {
    cvt4f8(w0, W0f8, T);
    return;
  }
  T -= 786432L;
  if (T < 786432L) {
    cvt4f8(w2, W2f8, T);
    return;
  }
  T -= 786432L;
  if (T < 65536L) {
    cvt4(ow, OWc, T);
    return;
  }
  T -= 65536L;
  // w1s (L,3,I,I,K=3) -> W1f8[(l*3+p)*I+i][t*1024 + j], value x64
  const long j4 = T & 255;   // group of 4 j's
  const long r3 = T >> 8;
  const float* src = w1 + r3 * 3072 + j4 * 12;
  const float4 v0 = *(const float4*)src;       // j0t0 j0t1 j0t2 j1t0
  const float4 v1 = *(const float4*)(src + 4); // j1t1 j1t2 j2t0 j2t1
  const float4 v2 = *(const float4*)(src + 8); // j2t2 j3t0 j3t1 j3t2
  u8* dst = W1f8 + r3 * 3072 + j4 * 4;
  *(int*)(dst) = pk4f8(v0.x * 64.f, v0.w * 64.f, v1.z * 64.f, v2.y * 64.f);
  *(int*)(dst + 1024) = pk4f8(v0.y * 64.f, v1.x * 64.f, v1.w * 64.f, v2.z * 64.f);
  *(int*)(dst + 2048) = pk4f8(v0.z * 64.f, v1.y * 64.f, v2.x * 64.f, v2.w * 64.f);
}

// One wave per (b,s) column: shfl-scan cumsum, stats, EMA; fuse next h (fp8)
// or final streams (bf16). R13: 256-thr blocks, 4 cols each (1024 blocks).
__global__ __launch_bounds__(256) void k_cell(const float* __restrict__ Y3,
                                              float* __restrict__ a_st,
                                              float* __restrict__ b_st,
                                              void* __restrict__ outp,
                                              int last) {
  const int col = (blockIdx.x << 2) + (threadIdx.x >> 6);
  const int s = col & (S_ - 1);
  const int b = col >> 11;
  const int lane = threadIdx.x & 63;
  const int f0 = lane * 8;
  const float* d = Y3 + ((long)(3 * b + 0) * S_ + s) * F_ + f0;
  const float* sc = Y3 + ((long)(3 * b + 1) * S_ + s) * F_ + f0;
  const float* sh = Y3 + ((long)(3 * b + 2) * S_ + s) * F_ + f0;
  float* ap = a_st + (long)col * F_ + f0;
  float* bp = b_st + (long)col * F_ + f0;
  const float inv_div = 1.0f / (float)(s + 1);

  const float4 d0 = *(const float4*)d;
  const float4 d1 = *(const float4*)(d + 4);
  const float4 sc0 = *(const float4*)sc;
  const float4 sc1 = *(const float4*)(sc + 4);
  const float4 sh0 = *(const float4*)sh;
  const float4 sh1 = *(const float4*)(sh + 4);

  float c[8];
  c[0] = d0.x;
  c[1] = c[0] + d0.y;
  c[2] = c[1] + d0.z;
  c[3] = c[2] + d0.w;
  c[4] = c[3] + d1.x;
  c[5] = c[4] + d1.y;
  c[6] = c[5] + d1.z;
  c[7] = c[6] + d1.w;
  const float tot = c[7];
  float scan = tot;
#pragma unroll
  for (int off = 1; off < 64; off <<= 1) {
    float nb = __shfl_up(scan, off);
    if (lane >= off) scan += nb;
  }
  const float base = scan - tot;

  float v[8];
  v[0] = (base + c[0]) * inv_div * sc0.x + sh0.x;
  v[1] = (base + c[1]) * inv_div * sc0.y + sh0.y;
  v[2] = (base + c[2]) * inv_div * sc0.z + sh0.z;
  v[3] = (base + c[3]) * inv_div * sc0.w + sh0.w;
  v[4] = (base + c[4]) * inv_div * sc1.x + sh1.x;
  v[5] = (base + c[5]) * inv_div * sc1.y + sh1.y;
  v[6] = (base + c[6]) * inv_div * sc1.z + sh1.z;
  v[7] = (base + c[7]) * inv_div * sc1.w + sh1.w;

  float sum = 0.f, ssq = 0.f;
#pragma unroll
  for (int q = 0; q < 8; ++q) {
    sum += v[q];
    ssq += v[q] * v[q];
  }
#pragma unroll
  for (int off = 1; off < 64; off <<= 1) {
    sum += __shfl_xor(sum, off);
    ssq += __shfl_xor(ssq, off);
  }
  const float mean = sum * (1.0f / (float)F_);
  const float nsq = fmaxf(ssq - (float)F_ * mean * mean, 0.0f);
  const float denom = sqrtf(nsq) * 0.04419417382415922f + 1e-5f;
  const float isc = 0.7071067811865476f / denom;

  const float4 av0 = *(const float4*)ap;
  const float4 av1 = *(const float4*)(ap + 4);
  const float4 bv0 = *(const float4*)bp;
  const float4 bv1 = *(const float4*)(bp + 4);
  float an[8], bn[8];
  const float ai[8] = {av0.x, av0.y, av0.z, av0.w, av1.x, av1.y, av1.z, av1.w};
  const float bi[8] = {bv0.x, bv0.y, bv0.z, bv0.w, bv1.x, bv1.y, bv1.z, bv1.w};
#pragma unroll
  for (int q = 0; q < 8; ++q) {
    const float cell = (v[q] - mean) * isc;
    an[q] = 0.99f * ai[q] + 0.01f * cell;
    bn[q] = bi[q] + an[q];
  }
  *(float4*)ap = {an[0], an[1], an[2], an[3]};
  *(float4*)(ap + 4) = {an[4], an[5], an[6], an[7]};
  *(float4*)bp = {bn[0], bn[1], bn[2], bn[3]};
  *(float4*)(bp + 4) = {bn[4], bn[5], bn[6], bn[7]};
  if (!last) {
    float hv[8];
#pragma unroll
    for (int q = 0; q < 8; ++q) hv[q] = bn[q] + fe_val(f0 + q);
    const int lo = pk4f8(hv[0], hv[1], hv[2], hv[3]);
    const int hi = pk4f8(hv[4], hv[5], hv[6], hv[7]);
    *(int2*)((u8*)outp + (long)col * F_ + f0) = {lo, hi};
  } else {
    bf8 oa, ob;
#pragma unroll
    for (int q = 0; q < 8; ++q) {
      oa[q] = (__bf16)an[q];
      ob[q] = (__bf16)bn[q];
    }
    *(bf8*)((__bf16*)outp + (long)col * (2 * F_) + f0) = oa;
    *(bf8*)((__bf16*)outp + (long)col * (2 * F_) + F_ + f0) = ob;
  }
}

// Fused logits GEMM (bf16) + bias + softmax + NLL.
// R13: 16-position tiles, grid (128,2) = 256 blocks (fills all 256 CUs; was
// 128). Last-block-done pattern absorbs k_final: after the block's atomicAdd,
// the 256th block to increment the counter reads acc and writes the output.
__global__ __launch_bounds__(256) void k_logits_nll(
    const __bf16* __restrict__ A, const __bf16* __restrict__ Bb,
    const float* __restrict__ outb, const int* __restrict__ tgt,
    float* __restrict__ acc, unsigned* __restrict__ cnt,
    float* __restrict__ out) {
  __shared__ __bf16 As[256 * 32];
  __shared__ __bf16 Bs[16 * 32];
  __shared__ float lsm[16 * 256];
  const int tid = threadIdx.x;
  const int b = blockIdx.y;
  const int n0 = blockIdx.x * 16;
  const __bf16* Bt = Bb + (long)b * (S_ * 2 * F_) + (long)n0 * (2 * F_);
  const int lane = tid & 63;
  const int wave = tid >> 6;
  const int l15 = lane & 15;
  const int quad = lane >> 4;
  const int cr = tid >> 2;
  const int csw = (((tid & 3) ^ ((cr >> 1) & 3)) << 3);
  const int roff = ((quad ^ ((l15 >> 1) & 3)) << 3);
  f4 av[4] = {};
  for (int k0 = 0; k0 < 2 * F_; k0 += 32) {
#pragma unroll
    for (int i = 0; i < 4; ++i)
      gload_lds16(A + (long)(i * 64 + cr) * (2 * F_) + (k0 + csw),
                  As + ((i * 256 + (wave << 6)) << 3));
    if (wave == 0)
      gload_lds16(Bt + (long)cr * (2 * F_) + (k0 + csw), Bs);
    __syncthreads();
    bf8 af[4], bf0;
#pragma unroll
    for (int mt = 0; mt < 4; ++mt)
      af[mt] = *(const bf8*)(As + (wave * 64 + mt * 16 + l15) * 32 + roff);
    bf0 = *(const bf8*)(Bs + (l15)*32 + roff);
#pragma unroll
    for (int mt = 0; mt < 4; ++mt)
      av[mt] = __builtin_amdgcn_mfma_f32_16x16x32_bf16(af[mt], bf0, av[mt], 0,
                                                       0, 0);
    __syncthreads();
  }
#pragma unroll
  for (int mt = 0; mt < 4; ++mt) {
    const int m = wave * 64 + mt * 16 + quad * 4;
    *(f4*)(lsm + l15 * C_ + m) = av[mt];
  }
  __syncthreads();
  const float4 bv = *(const float4*)(outb + lane * 4);
  float wsum = 0.f;
  for (int i = 0; i < 4; ++i) {
    const int pp = wave * 4 + i;
    const f4 lv = *(const f4*)(lsm + pp * C_ + lane * 4);
    const float x0 = lv[0] + bv.x, x1 = lv[1] + bv.y, x2 = lv[2] + bv.z,
                x3 = lv[3] + bv.w;
    float mx = fmaxf(fmaxf(x0, x1), fmaxf(x2, x3));
#pragma unroll
    for (int off = 1; off < 64; off <<= 1) mx = fmaxf(mx, __shfl_xor(mx, off));
    float ss = expf(x0 - mx) + expf(x1 - mx) + expf(x2 - mx) + expf(x3 - mx);
#pragma unroll
    for (int off = 1; off < 64; off <<= 1) ss += __shfl_xor(ss, off);
    if (lane == 0) {
      const int t = tgt[b * S_ + n0 + pp];
      wsum += mx + logf(ss) - (lsm[pp * C_ + t] + outb[t]);
    }
  }
  if (lane == 0) atomicAdd(acc, wsum);
  __syncthreads();  // all waves' atomics issued + drained (barrier waitcnt)
  if (tid == 0) {
    const unsigned nblk = gridDim.x * gridDim.y;
    const unsigned old = atomicAdd(cnt, 1u);
    if (old == nblk - 1) {
      const float v = atomicAdd(acc, 0.0f);  // atomic read: coherent
      out[0] = v * (1.0f / 4096.0f);
    }
  }
}

extern "C" void kernel_launch(void* const* d_in, const int* in_sizes, int n_in,
                              void* d_out, int out_size, void* d_ws,
                              size_t ws_size, hipStream_t stream) {
  const int* inp = (const int*)d_in[0];
  const int* tgt = (const int*)d_in[1];
  const float* emb = (const float*)d_in[2];
  const float* w0s = (const float*)d_in[3];
  const float* w1s = (const float*)d_in[4];
  const float* w2s = (const float*)d_in[5];
  const float* out_w = (const float*)d_in[6];
  const float* out_b = (const float*)d_in[7];

  char* ws = (char*)d_ws;
  float* acc = (float*)(ws + 0);
  unsigned* cnt = (unsigned*)(ws + 16);
  u8* zp = (u8*)(ws + 256);
  float* a_st = (float*)(ws + 4096);
  float* b_st = (float*)(ws + 8392704L);
  u8* h = (u8*)(ws + 16781312L);            // [b*2048+s][512] fp8
  u8* Y1f8 = (u8*)(ws + 20975616L);         // [b][s][3072] fp8
  u8* Y2f8 = (u8*)(ws + 46141440L);         // [b*3+p][s][1024] fp8
  float* Y3 = (float*)(ws + 71307264L);     // [b*3+p][s][512] f32
  u8* W1f8 = (u8*)(ws + 96473088L);         // [(l*3+p)*I+i][3072] fp8 x64
  __bf16* streams = (__bf16*)(ws + 134221824L);
  u8* W0f8 = (u8*)(ws + 146804736L);        // [l][3072][512] fp8 x64
  u8* W2f8 = (u8*)(ws + 153096192L);        // [l][3*512][1024] fp8 x64
  __bf16* OWc = (__bf16*)(ws + 159387648L);

  // One merged prologue dispatch: weight conversion + embedding + ws zeroing
  // (replaces hipMemsetAsync + k_prep + k_embed: 3 dispatches -> 1).
  k_prep<<<13569, 256, 0, stream>>>(w0s, w2s, out_w, w1s, W0f8, W2f8, OWc,
                                    W1f8, inp, emb, a_st, b_st, h, (int*)ws);

  for (int l = 0; l < 2; ++l) {
    // conv1: (3I x F) @ h -> Y1 fp8, relu
    gemm_f8<1, true, 2, 128, 512, 512><<<dim3(16, 24, 2), 256, 0, stream>>>(
        W0f8 + (long)l * 1572864L, h, Y1f8, zp, 3072, 1, 0L, 0L, 1048576L,
        6291456L);
    // conv2: causal k=3 (I x 3I) -> Y2 fp8, relu
    gemm_f8<3, true, 2, 128, 1024, 3072><<<dim3(16, 8, 6), 256, 0, stream>>>(
        W1f8 + (long)l * 9437184L, Y1f8, Y2f8, zp, 1024, 3, 3145728L, 1024L,
        6291456L, 2097152L);
    // conv3: (F x I) @ Y2 -> Y3 f32
    gemm_f8<1, false, 0, 64, 1024, 1024><<<dim3(32, 4, 6), 256, 0, stream>>>(
        W2f8 + (long)l * 1572864L, Y2f8, Y3, zp, 512, 3, 524288L, 2097152L,
        6291456L, 1048576L);
    k_cell<<<1024, 256, 0, stream>>>(Y3, a_st, b_st,
                                     (l == 0) ? (void*)h : (void*)streams,
                                     (l == 1) ? 1 : 0);
  }

  // Fused logits+NLL; last block writes the final mean (absorbs k_final).
  k_logits_nll<<<dim3(128, 2), 256, 0, stream>>>(OWc, streams, out_b, tgt, acc,
                                                 cnt, (float*)d_out);
}